// Round 6
// baseline (359.965 us; speedup 1.0000x reference)
//
#include <hip/hip_runtime.h>
#include <math.h>

#define NRAYS 16384
#define HID 64
#define NS 128
#define NUP 128
#define STOT 256

typedef float  float4_ __attribute__((ext_vector_type(4)));
typedef short  short8  __attribute__((ext_vector_type(8)));

#define LGKM0() __asm__ __volatile__("s_waitcnt lgkmcnt(0)" ::: "memory")

__device__ __forceinline__ float clip1(float v){ return fminf(fmaxf(v,-1.f),1.f); }
__device__ __forceinline__ float softplusf(float x){ return fmaxf(x,0.f)+log1pf(expf(-fabsf(x))); }
__device__ __forceinline__ float sigmoidf(float x){ return 1.f/(1.f+expf(-x)); }

__device__ __forceinline__ unsigned short f2bf(float f){          // RNE (prep only)
  unsigned int u = __float_as_uint(f);
  u = (u + 0x7fffu + ((u>>16)&1u)) >> 16;
  return (unsigned short)u;
}
// pack 2 floats -> 2 bf16 (round-half-up): a -> low16, b -> high16
__device__ __forceinline__ unsigned int pk2bf(float a, float b){
  unsigned int au = __float_as_uint(a) + 0x8000u;
  unsigned int bu = __float_as_uint(b) + 0x8000u;
  return __builtin_amdgcn_perm(bu, au, 0x07060302u);
}

__device__ __forceinline__ void load_ray(const float* ro, const float* rd, int r,
    float& ox,float& oy,float& oz,float& dx,float& dy,float& dz){
  ox=ro[3*r]; oy=ro[3*r+1]; oz=ro[3*r+2];
  dx=rd[3*r]; dy=rd[3*r+1]; dz=rd[3*r+2];
  float inv = 1.f/sqrtf(dx*dx+dy*dy+dz*dz);
  dx*=inv; dy*=inv; dz*=inv;
}

__device__ __forceinline__ void aabb_nf(float ox,float oy,float oz,float dx,float dy,float dz,
    float& nears,float& fars){
  float dsx = (fabsf(dx)<1e-8f)?1e-8f:dx;
  float dsy = (fabsf(dy)<1e-8f)?1e-8f:dy;
  float dsz = (fabsf(dz)<1e-8f)?1e-8f:dz;
  float t1x=(-1.f-ox)/dsx, t2x=(1.f-ox)/dsx;
  float t1y=(-1.f-oy)/dsy, t2y=(1.f-oy)/dsy;
  float t1z=(-1.f-oz)/dsz, t2z=(1.f-oz)/dsz;
  float nr = fmaxf(fmaxf(fminf(t1x,t2x),fminf(t1y,t2y)),fminf(t1z,t2z));
  float fr = fminf(fminf(fmaxf(t1x,t2x),fmaxf(t1y,t2y)),fmaxf(t1z,t2z));
  fars  = fmaxf(fminf(fr,5.f),0.2f);
  nears = fminf(fmaxf(nr,0.2f),5.f);
}

// exclusive block scan over 256 threads / 4 waves (contains __syncthreads)
__device__ __forceinline__ float block_excl_scan(float v, float* lds_ws,
    int tid, float& total){
  float incl = v;
  #pragma unroll
  for(int off=1; off<64; off<<=1){
    float n = __shfl_up(incl, off, 64);
    if ((tid & 63) >= off) incl += n;
  }
  int wv = tid >> 6;
  if ((tid & 63) == 63) lds_ws[wv] = incl;
  __syncthreads();
  float woff = 0.f, tot = 0.f;
  #pragma unroll
  for(int k=0;k<4;k++){ float s = lds_ws[k]; tot += s; if (k < wv) woff += s; }
  __syncthreads();
  total = tot;
  return woff + incl - v;
}

// ---------------- weight prep: A-fragments (transposed weights) ----------------
// A-frag: lane l holds A[m=l&15][k=(l>>4)*8+j], j=0..7. 12 slots of 64 lanes x 8 ushorts:
// slots 0..3 : W1^T  (M-tile mt: m=h=mt*16+c):  A = W1[k][h], k>=3 -> 0
// slots 4..5 : W2^T  (K-step ks: k=h=ks*32+..): A = W2[h][od=c]
// slots 6..9 : Wc1^T (M-tile mt), PERMUTED k:   k=0 -> 0 row; k in 1..15 -> geo_{k-1}
//              (Wc1 row 5+k); k in 16..21 -> pos/dir (Wc1 row k-16); k>=22 -> 0
// slots 10..11: Wc2^T: A = (c<3)? Wc2[h][c] : 0
__global__ void prep_weights(const float* __restrict__ W1, const float* __restrict__ W2,
                             const float* __restrict__ Wc1, const float* __restrict__ Wc2,
                             unsigned short* __restrict__ wb){
  int idx = blockIdx.x*256 + threadIdx.x;
  if (idx >= 6144) return;
  int f = idx>>3, j = idx&7, lane = f&63, slot = f>>6, q = lane>>4, c = lane&15;
  int k = q*8+j;
  float v = 0.f;
  if (slot < 4){        if (k<3) v = W1[k*HID + slot*16 + c]; }
  else if (slot < 6){   int h=(slot-4)*32+k; v = W2[h*16 + c]; }
  else if (slot < 10){  int mt=slot-6;
                        int row = (k==0)? -1 : (k<16 ? 5+k : (k<22 ? k-16 : -1));
                        if (row>=0) v = Wc1[row*HID + mt*16 + c]; }
  else {                int h=(slot-10)*32+k; if (c<3) v = Wc2[h*3 + c]; }
  wb[idx] = f2bf(v);
}

// ================= fully fused NeRF kernel: 256 threads / ray-block =================
// H layout (per wave, 1024 ushorts): frag-major. Reader lane l gets its layer-2
// B-frag at l*16B (frag0) / 1024B + l*16B (frag1) -> conflict-free lane-linear reads.
// Writer (q,c), C-tile t (h=t*16+q*4..+3, sample c): u64 at (q>>1)*256+c*16+(q&1)*8
// + t*512 bytes -> 2-way bank alias (free). Geo chunk (per wave, 256 ushorts): same
// writer pattern (q'=0,1 chunks only); reader lanes q<2 read lane-linear.
__global__ __launch_bounds__(256) void nerf_fused(
    const float* __restrict__ ro, const float* __restrict__ rd,
    const float* __restrict__ b1, const float* __restrict__ b2,
    const float* __restrict__ bc1, const float* __restrict__ bc2,
    const unsigned short* __restrict__ wb, float* __restrict__ out)
{
  __shared__ __align__(16) unsigned short Hfrag[4][1024];  // 8 KB
  __shared__ __align__(16) unsigned short Geo[4][256];     // 2 KB
  __shared__ float sigC[128], sigF[128], newzL[128], cdf[128], zBs[128];
  __shared__ float zM[257], sM[256], wL[256];
  __shared__ float sws[4], red[16];

  const int r = blockIdx.x;
  const int s = threadIdx.x, lane = s&63, wv = s>>6;
  const int q = lane>>4, c = lane&15;

  float ox,oy,oz,dx,dy,dz;
  load_ray(ro,rd,r,ox,oy,oz,dx,dy,dz);
  float nears,fars; aabb_nf(ox,oy,oz,dx,dy,dz,nears,fars);
  const float step  = (fars-nears)*(1.f/127.f);
  const float sdist = (fars-nears)*(1.f/128.f);
  const bool asc = (nears <= fars);

  const short8* WF = (const short8*)wb;
  short8 aW1T[4], aW2T[2], aWc1T[4], aWc2T[2];
  #pragma unroll
  for(int t=0;t<4;t++){ aW1T[t] = WF[t*64+lane]; aWc1T[t] = WF[(6+t)*64+lane]; }
  #pragma unroll
  for(int k=0;k<2;k++){ aW2T[k] = WF[(4+k)*64+lane]; aWc2T[k] = WF[(10+k)*64+lane]; }
  float4_ b1v[4], bc1v[4];
  #pragma unroll
  for(int t=0;t<4;t++){
    b1v[t]  = *(const float4_*)&b1[t*16+q*4];
    bc1v[t] = *(const float4_*)&bc1[t*16+q*4];
  }
  const float4_ bTd = *(const float4_*)&b2[q*4];
  float4_ bTc = (float4_){0.f,0.f,0.f,0.f};
  if (q==0){ bTc[0]=bc2[0]; bTc[1]=bc2[1]; bTc[2]=bc2[2]; }

  unsigned short* Hw = Hfrag[wv];
  unsigned short* Gw = Geo[wv];
  const int hbase = (q>>1)*128 + c*8 + (q&1)*4;   // ushort index
  const int lread = lane*8;                        // ushort index

  // ---------- coarse (pass 0) + pdf + fine (pass 1) ----------
  for(int pass=0; pass<2; pass++){
    if (pass==1){
      // pdf from coarse sigmas; exp-space scan of d_i = step*sigma_i
      float d = (s<127) ? step * sigC[s] : 0.f;
      float tot;
      float S = block_excl_scan(d, sws, s, tot);
      float w = (s<127) ? (1.f - expf(-d)) * expf(-S) : 0.f;
      float ww = (s>=1 && s<127) ? (w + 1e-5f) : 0.f;
      float wsum;
      float ce = block_excl_scan(ww, sws, s, wsum);
      if (s<127) cdf[s] = (ce+ww)/wsum;
      __syncthreads();
      if (s<128){
        const float u0 = 0.5f/128.f;
        const float du = (1.f - 1.f/128.f)/127.f;
        float u = u0 + du*(float)s;
        int lo=0, hi=127;
        while(lo<hi){ int m=(lo+hi)>>1; if (cdf[m] <= u) lo=m+1; else hi=m; }
        int below = max(lo-1,0), above = min(lo,126);
        float c0 = cdf[below], c1 = cdf[above];
        float bb0 = nears + step*((float)below + 0.5f);
        float bb1 = nears + step*((float)above + 0.5f);
        float den = c1 - c0; if (den < 1e-5f) den = 1.f;
        float zf = bb0 + (u - c0)/den*(bb1 - bb0);
        newzL[s] = zf;
        zBs[asc ? s : 127-s] = zf;   // ascending-sorted fine list
      }
      __syncthreads();
    }

    #pragma unroll
    for(int g=0; g<2; g++){
      int sidx = wv*32 + g*16 + c;
      short8 bf = (short8){0,0,0,0,0,0,0,0};
      if (q==0){
        float z = pass ? newzL[sidx] : fmaf(step, (float)sidx, nears);
        unsigned int* bu = (unsigned int*)&bf;
        bu[0] = pk2bf(clip1(fmaf(dx,z,ox)), clip1(fmaf(dy,z,oy)));
        bu[1] = pk2bf(clip1(fmaf(dz,z,oz)), 0.f);
      }
      float4_ acc;
      #pragma unroll
      for(int t=0;t<4;t++){
        acc = b1v[t];
        acc = __builtin_amdgcn_mfma_f32_16x16x32_bf16(aW1T[t], bf, acc, 0,0,0);
        unsigned long long dd =
            (unsigned long long)pk2bf(fmaxf(acc[0],0.f), fmaxf(acc[1],0.f))
          | ((unsigned long long)pk2bf(fmaxf(acc[2],0.f), fmaxf(acc[3],0.f))<<32);
        *(unsigned long long*)&Hw[hbase + t*256] = dd;
      }
      LGKM0();
      short8 h0 = *(const short8*)&Hw[lread];
      short8 h1 = *(const short8*)&Hw[512 + lread];
      float4_ o = bTd;
      o = __builtin_amdgcn_mfma_f32_16x16x32_bf16(aW2T[0], h0, o, 0,0,0);
      o = __builtin_amdgcn_mfma_f32_16x16x32_bf16(aW2T[1], h1, o, 0,0,0);
      if (q==0){ (pass ? sigF : sigC)[sidx] = softplusf(o[0]); }
      LGKM0();
    }
    __syncthreads();
  }

  // ---------- merge (coarse grid is linear -> computed binary search) ----------
  {
    float myz, mysig; int pos;
    if (s < 128){
      int i = asc ? s : 127-s;
      myz = fmaf(step, (float)i, nears);
      mysig = sigC[i];
      int lo=0, hi=128;
      while(lo<hi){ int m=(lo+hi)>>1; if (zBs[m] < myz) lo=m+1; else hi=m; }
      pos = s + lo;
    } else {
      int k = s-128;
      myz = zBs[k];
      mysig = sigF[asc ? k : 127-k];
      int lo=0, hi=128;
      while(lo<hi){
        int m=(lo+hi)>>1;
        float Am = fmaf(step, (float)(asc ? m : 127-m), nears);
        if (Am <= myz) lo=m+1; else hi=m;
      }
      pos = k + lo;
    }
    zM[pos]=myz; sM[pos]=mysig;
    __syncthreads();
  }

  // ---------- composite (exp-space scan) ----------
  {
    float zs = zM[s], sgs = sM[s];
    float delta = (s < STOT-1) ? (zM[s+1] - zs) : sdist;
    float d = delta*sgs;
    float tot;
    float S = block_excl_scan(d, sws, s, tot);
    wL[s] = (1.f - expf(-d)) * expf(-S);
  }
  LGKM0();   // wave-local wL/zM reads below; cross-wave covered by scan's syncs

  // ---------- render: density->geo->color per 16-sample group ----------
  float accR=0.f, accG=0.f, accB=0.f, accW=0.f;
  #pragma unroll
  for(int g=0; g<4; g++){
    const int sidx = wv*64 + g*16 + c;
    float x=0.f, y=0.f, zz=0.f;
    if ((q&1)==0){
      float zq = zM[sidx];     // q0 & q2 same address -> broadcast
      x = clip1(fmaf(dx,zq,ox)); y = clip1(fmaf(dy,zq,oy)); zz = clip1(fmaf(dz,zq,oz));
    }
    short8 bf = (short8){0,0,0,0,0,0,0,0};
    if (q==0){
      unsigned int* bu = (unsigned int*)&bf;
      bu[0] = pk2bf(x,y); bu[1] = pk2bf(zz,0.f);
    }
    float4_ acc;
    #pragma unroll
    for(int t=0;t<4;t++){
      acc = b1v[t];
      acc = __builtin_amdgcn_mfma_f32_16x16x32_bf16(aW1T[t], bf, acc, 0,0,0);
      unsigned long long dd =
          (unsigned long long)pk2bf(fmaxf(acc[0],0.f), fmaxf(acc[1],0.f))
        | ((unsigned long long)pk2bf(fmaxf(acc[2],0.f), fmaxf(acc[3],0.f))<<32);
      *(unsigned long long*)&Hw[hbase + t*256] = dd;
    }
    LGKM0();
    short8 h0 = *(const short8*)&Hw[lread];
    short8 h1 = *(const short8*)&Hw[512 + lread];
    float4_ o = bTd;
    o = __builtin_amdgcn_mfma_f32_16x16x32_bf16(aW2T[0], h0, o, 0,0,0);
    o = __builtin_amdgcn_mfma_f32_16x16x32_bf16(aW2T[1], h1, o, 0,0,0);
    // geo (raw, no relu): ods q*4..+3 of sample c -> Geo chunk (frag-major)
    {
      unsigned long long dd =
          (unsigned long long)pk2bf(o[0],o[1])
        | ((unsigned long long)pk2bf(o[2],o[3])<<32);
      *(unsigned long long*)&Gw[hbase] = dd;
    }
    LGKM0();
    short8 bcf = (short8){0,0,0,0,0,0,0,0};
    if (q < 2){
      bcf = *(const short8*)&Gw[lread];     // k = q*8..q*8+7 (geo ods)
    } else if (q == 2){
      unsigned int* bu = (unsigned int*)&bcf;   // k16..21 = pos/dir
      bu[0] = pk2bf(x,y); bu[1] = pk2bf(zz,dx); bu[2] = pk2bf(dy,dz); bu[3] = 0u;
    }
    #pragma unroll
    for(int t=0;t<4;t++){
      acc = bc1v[t];
      acc = __builtin_amdgcn_mfma_f32_16x16x32_bf16(aWc1T[t], bcf, acc, 0,0,0);
      unsigned long long dd =
          (unsigned long long)pk2bf(fmaxf(acc[0],0.f), fmaxf(acc[1],0.f))
        | ((unsigned long long)pk2bf(fmaxf(acc[2],0.f), fmaxf(acc[3],0.f))<<32);
      *(unsigned long long*)&Hw[hbase + t*256] = dd;
    }
    LGKM0();
    h0 = *(const short8*)&Hw[lread];
    h1 = *(const short8*)&Hw[512 + lread];
    float4_ oc = bTc;
    oc = __builtin_amdgcn_mfma_f32_16x16x32_bf16(aWc2T[0], h0, oc, 0,0,0);
    oc = __builtin_amdgcn_mfma_f32_16x16x32_bf16(aWc2T[1], h1, oc, 0,0,0);
    if (q==0){
      float wgt = wL[sidx];
      if (wgt > 1e-4f){
        accR = fmaf(wgt, sigmoidf(oc[0]), accR);
        accG = fmaf(wgt, sigmoidf(oc[1]), accG);
        accB = fmaf(wgt, sigmoidf(oc[2]), accB);
      }
      accW += wgt;
    }
    LGKM0();
  }

  // ---------- reduce ----------
  #pragma unroll
  for(int off=32; off; off>>=1){
    accR += __shfl_down(accR, off, 64);
    accG += __shfl_down(accG, off, 64);
    accB += __shfl_down(accB, off, 64);
    accW += __shfl_down(accW, off, 64);
  }
  if (lane == 0){ red[wv*4+0]=accR; red[wv*4+1]=accG; red[wv*4+2]=accB; red[wv*4+3]=accW; }
  __syncthreads();
  if (s == 0){
    float R=0.f,G=0.f,B=0.f,W=0.f;
    #pragma unroll
    for(int k=0;k<4;k++){ R+=red[k*4+0]; G+=red[k*4+1]; B+=red[k*4+2]; W+=red[k*4+3]; }
    float bg = 1.f - W;
    out[r*3+0] = R + bg;
    out[r*3+1] = G + bg;
    out[r*3+2] = B + bg;
  }
}

extern "C" void kernel_launch(void* const* d_in, const int* in_sizes, int n_in,
                              void* d_out, int out_size, void* d_ws, size_t ws_size,
                              hipStream_t stream) {
  const float* ro  = (const float*)d_in[0];
  const float* rd  = (const float*)d_in[1];
  const float* W1  = (const float*)d_in[2];
  const float* b1  = (const float*)d_in[3];
  const float* W2  = (const float*)d_in[4];
  const float* b2  = (const float*)d_in[5];
  const float* Wc1 = (const float*)d_in[6];
  const float* bc1 = (const float*)d_in[7];
  const float* Wc2 = (const float*)d_in[8];
  const float* bc2 = (const float*)d_in[9];
  float* out = (float*)d_out;

  unsigned short* wb = (unsigned short*)d_ws;   // 6144 bf16 fragment words

  prep_weights<<<dim3(24), dim3(256), 0, stream>>>(W1, W2, Wc1, Wc2, wb);
  nerf_fused<<<dim3(NRAYS), dim3(256), 0, stream>>>(
      ro, rd, b1, b2, bc1, bc2, wb, out);
}

// Round 7
// 281.744 us; speedup vs baseline: 1.2776x; 1.2776x over previous
//
#include <hip/hip_runtime.h>
#include <math.h>

#define NRAYS 16384
#define HID 64
#define NS 128
#define NUP 128
#define STOT 256

typedef float  float4_ __attribute__((ext_vector_type(4)));
typedef short  short8  __attribute__((ext_vector_type(8)));

#define LGKM0() __asm__ __volatile__("s_waitcnt lgkmcnt(0)" ::: "memory")

__device__ __forceinline__ float clip1(float v){ return fminf(fmaxf(v,-1.f),1.f); }
__device__ __forceinline__ float softplusf_(float x){
  return fmaxf(x,0.f) + __logf(1.f + __expf(-fabsf(x)));
}
__device__ __forceinline__ float sigmoidf_(float x){
  return __fdividef(1.f, 1.f + __expf(-x));
}

__device__ __forceinline__ unsigned short f2bf(float f){          // RNE (prep only)
  unsigned int u = __float_as_uint(f);
  u = (u + 0x7fffu + ((u>>16)&1u)) >> 16;
  return (unsigned short)u;
}
// pack 2 floats -> 2 bf16 (round-half-up): a -> low16, b -> high16
__device__ __forceinline__ unsigned int pk2bf(float a, float b){
  unsigned int au = __float_as_uint(a) + 0x8000u;
  unsigned int bu = __float_as_uint(b) + 0x8000u;
  return __builtin_amdgcn_perm(bu, au, 0x07060302u);
}

__device__ __forceinline__ void load_ray(const float* ro, const float* rd, int r,
    float& ox,float& oy,float& oz,float& dx,float& dy,float& dz){
  ox=ro[3*r]; oy=ro[3*r+1]; oz=ro[3*r+2];
  dx=rd[3*r]; dy=rd[3*r+1]; dz=rd[3*r+2];
  float inv = 1.f/sqrtf(dx*dx+dy*dy+dz*dz);
  dx*=inv; dy*=inv; dz*=inv;
}

__device__ __forceinline__ void aabb_nf(float ox,float oy,float oz,float dx,float dy,float dz,
    float& nears,float& fars){
  float dsx = (fabsf(dx)<1e-8f)?1e-8f:dx;
  float dsy = (fabsf(dy)<1e-8f)?1e-8f:dy;
  float dsz = (fabsf(dz)<1e-8f)?1e-8f:dz;
  float t1x=(-1.f-ox)/dsx, t2x=(1.f-ox)/dsx;
  float t1y=(-1.f-oy)/dsy, t2y=(1.f-oy)/dsy;
  float t1z=(-1.f-oz)/dsz, t2z=(1.f-oz)/dsz;
  float nr = fmaxf(fmaxf(fminf(t1x,t2x),fminf(t1y,t2y)),fminf(t1z,t2z));
  float fr = fminf(fminf(fmaxf(t1x,t2x),fmaxf(t1y,t2y)),fmaxf(t1z,t2z));
  fars  = fmaxf(fminf(fr,5.f),0.2f);
  nears = fminf(fmaxf(nr,0.2f),5.f);
}

// exclusive block scan over 256 threads / 4 waves (contains __syncthreads)
__device__ __forceinline__ float block_excl_scan(float v, float* lds_ws,
    int tid, float& total){
  float incl = v;
  #pragma unroll
  for(int off=1; off<64; off<<=1){
    float n = __shfl_up(incl, off, 64);
    if ((tid & 63) >= off) incl += n;
  }
  int wv = tid >> 6;
  if ((tid & 63) == 63) lds_ws[wv] = incl;
  __syncthreads();
  float woff = 0.f, tot = 0.f;
  #pragma unroll
  for(int k=0;k<4;k++){ float s = lds_ws[k]; tot += s; if (k < wv) woff += s; }
  __syncthreads();
  total = tot;
  return woff + incl - v;
}

// ---------------- weight prep: A-fragments (transposed weights) ----------------
// A-frag: lane l holds A[m=l&15][k=(l>>4)*8+j], j=0..7. 12 slots of 64 lanes x 8 ushorts:
// slots 0..3 : W1^T  (M-tile mt: m=h=mt*16+c):  A = W1[k][h], k>=3 -> 0
// slots 4..5 : W2^T  (K-step ks: k=h=ks*32+..): A = W2[h][od=c]
// slots 6..9 : Wc1^T (M-tile mt), PERMUTED k:   k=0 -> 0 row (od0=sigma unused);
//              k in 1..15 -> geo_{k-1} (Wc1 row 5+k); k in 16..21 -> pos/dir
//              (Wc1 row k-16); k>=22 -> 0
// slots 10..11: Wc2^T: A = (c<3)? Wc2[h][c] : 0
__global__ void prep_weights(const float* __restrict__ W1, const float* __restrict__ W2,
                             const float* __restrict__ Wc1, const float* __restrict__ Wc2,
                             unsigned short* __restrict__ wb){
  int idx = blockIdx.x*256 + threadIdx.x;
  if (idx >= 6144) return;
  int f = idx>>3, j = idx&7, lane = f&63, slot = f>>6, q = lane>>4, c = lane&15;
  int k = q*8+j;
  float v = 0.f;
  if (slot < 4){        if (k<3) v = W1[k*HID + slot*16 + c]; }
  else if (slot < 6){   int h=(slot-4)*32+k; v = W2[h*16 + c]; }
  else if (slot < 10){  int mt=slot-6;
                        int row = (k==0)? -1 : (k<16 ? 5+k : (k<22 ? k-16 : -1));
                        if (row>=0) v = Wc1[row*HID + mt*16 + c]; }
  else {                int h=(slot-10)*32+k; if (c<3) v = Wc2[h*3 + c]; }
  wb[idx] = f2bf(v);
}

// ================= fully fused NeRF kernel: 256 threads / ray-block =================
// Density MLP runs ONLY in the coarse/fine passes; the full 16-od output tile
// (sigma + geo) is packed to GeoAll[sample][16] there. The render phase gathers
// geo via the merge's oid map and runs only the color MLP (6 MFMA/group).
__global__ __launch_bounds__(256) void nerf_fused(
    const float* __restrict__ ro, const float* __restrict__ rd,
    const float* __restrict__ b1, const float* __restrict__ b2,
    const float* __restrict__ bc1, const float* __restrict__ bc2,
    const unsigned short* __restrict__ wb, float* __restrict__ out)
{
  __shared__ __align__(16) unsigned short Hfrag[4][1024];  // 8 KB
  __shared__ __align__(16) unsigned short GeoAll[256*16];  // 8 KB: od0..15 per sample
  __shared__ float sigC[128], sigF[128], newzL[128], cdf[128], zBs[128];
  __shared__ float zM[257], sM[256], wL[256];
  __shared__ unsigned short oidM[256];
  __shared__ float sws[4], red[16];

  const int r = blockIdx.x;
  const int s = threadIdx.x, lane = s&63, wv = s>>6;
  const int q = lane>>4, c = lane&15;

  float ox,oy,oz,dx,dy,dz;
  load_ray(ro,rd,r,ox,oy,oz,dx,dy,dz);
  float nears,fars; aabb_nf(ox,oy,oz,dx,dy,dz,nears,fars);
  const float step  = (fars-nears)*(1.f/127.f);
  const float sdist = (fars-nears)*(1.f/128.f);
  const bool asc = (nears <= fars);

  const short8* WF = (const short8*)wb;
  short8 aW1T[4], aW2T[2], aWc1T[4], aWc2T[2];
  #pragma unroll
  for(int t=0;t<4;t++){ aW1T[t] = WF[t*64+lane]; aWc1T[t] = WF[(6+t)*64+lane]; }
  #pragma unroll
  for(int k=0;k<2;k++){ aW2T[k] = WF[(4+k)*64+lane]; aWc2T[k] = WF[(10+k)*64+lane]; }
  float4_ b1v[4], bc1v[4];
  #pragma unroll
  for(int t=0;t<4;t++){
    b1v[t]  = *(const float4_*)&b1[t*16+q*4];
    bc1v[t] = *(const float4_*)&bc1[t*16+q*4];
  }
  const float4_ bTd = *(const float4_*)&b2[q*4];
  float4_ bTc = (float4_){0.f,0.f,0.f,0.f};
  if (q==0){ bTc[0]=bc2[0]; bTc[1]=bc2[1]; bTc[2]=bc2[2]; }

  unsigned short* Hw = Hfrag[wv];
  const int hbase = (q>>1)*128 + c*8 + (q&1)*4;   // ushort index
  const int lread = lane*8;                        // ushort index

  // ---------- coarse (pass 0) + pdf + fine (pass 1) ----------
  for(int pass=0; pass<2; pass++){
    if (pass==1){
      // pdf from coarse sigmas; exp-space scan of d_i = step*sigma_i
      float d = (s<127) ? step * sigC[s] : 0.f;
      float tot;
      float S = block_excl_scan(d, sws, s, tot);
      float w = (s<127) ? (1.f - __expf(-d)) * __expf(-S) : 0.f;
      float ww = (s>=1 && s<127) ? (w + 1e-5f) : 0.f;
      float wsum;
      float ce = block_excl_scan(ww, sws, s, wsum);
      if (s<127) cdf[s] = (ce+ww)/wsum;
      __syncthreads();
      if (s<128){
        const float u0 = 0.5f/128.f;
        const float du = (1.f - 1.f/128.f)/127.f;
        float u = u0 + du*(float)s;
        int lo=0, hi=127;
        while(lo<hi){ int m=(lo+hi)>>1; if (cdf[m] <= u) lo=m+1; else hi=m; }
        int below = max(lo-1,0), above = min(lo,126);
        float c0 = cdf[below], c1 = cdf[above];
        float bb0 = nears + step*((float)below + 0.5f);
        float bb1 = nears + step*((float)above + 0.5f);
        float den = c1 - c0; if (den < 1e-5f) den = 1.f;
        float zf = bb0 + (u - c0)/den*(bb1 - bb0);
        newzL[s] = zf;
        zBs[asc ? s : 127-s] = zf;   // ascending-sorted fine list
      }
      __syncthreads();
    }

    #pragma unroll
    for(int g=0; g<2; g++){
      int sidx = wv*32 + g*16 + c;
      short8 bf = (short8){0,0,0,0,0,0,0,0};
      if (q==0){
        float z = pass ? newzL[sidx] : fmaf(step, (float)sidx, nears);
        unsigned int* bu = (unsigned int*)&bf;
        bu[0] = pk2bf(clip1(fmaf(dx,z,ox)), clip1(fmaf(dy,z,oy)));
        bu[1] = pk2bf(clip1(fmaf(dz,z,oz)), 0.f);
      }
      float4_ acc;
      #pragma unroll
      for(int t=0;t<4;t++){
        acc = b1v[t];
        acc = __builtin_amdgcn_mfma_f32_16x16x32_bf16(aW1T[t], bf, acc, 0,0,0);
        unsigned long long dd =
            (unsigned long long)pk2bf(fmaxf(acc[0],0.f), fmaxf(acc[1],0.f))
          | ((unsigned long long)pk2bf(fmaxf(acc[2],0.f), fmaxf(acc[3],0.f))<<32);
        *(unsigned long long*)&Hw[hbase + t*256] = dd;
      }
      LGKM0();
      short8 h0 = *(const short8*)&Hw[lread];
      short8 h1 = *(const short8*)&Hw[512 + lread];
      float4_ o = bTd;
      o = __builtin_amdgcn_mfma_f32_16x16x32_bf16(aW2T[0], h0, o, 0,0,0);
      o = __builtin_amdgcn_mfma_f32_16x16x32_bf16(aW2T[1], h1, o, 0,0,0);
      // full od tile (sigma + geo, raw) -> GeoAll[sample][q*4..q*4+3]
      {
        unsigned long long dd =
            (unsigned long long)pk2bf(o[0],o[1])
          | ((unsigned long long)pk2bf(o[2],o[3])<<32);
        *(unsigned long long*)&GeoAll[(pass*128 + sidx)*16 + q*4] = dd;
      }
      if (q==0){ (pass ? sigF : sigC)[sidx] = softplusf_(o[0]); }
      LGKM0();
    }
    __syncthreads();
  }

  // ---------- merge (coarse grid is linear -> computed binary search) ----------
  {
    float myz, mysig; int pos, oid;
    if (s < 128){
      int i = asc ? s : 127-s;
      myz = fmaf(step, (float)i, nears);
      mysig = sigC[i];
      oid = i;
      int lo=0, hi=128;
      while(lo<hi){ int m=(lo+hi)>>1; if (zBs[m] < myz) lo=m+1; else hi=m; }
      pos = s + lo;
    } else {
      int k = s-128;
      myz = zBs[k];
      int fo = asc ? k : 127-k;
      mysig = sigF[fo];
      oid = 128 + fo;
      int lo=0, hi=128;
      while(lo<hi){
        int m=(lo+hi)>>1;
        float Am = fmaf(step, (float)(asc ? m : 127-m), nears);
        if (Am <= myz) lo=m+1; else hi=m;
      }
      pos = k + lo;
    }
    zM[pos]=myz; sM[pos]=mysig; oidM[pos]=(unsigned short)oid;
    __syncthreads();
  }

  // ---------- composite (exp-space scan) ----------
  {
    float zs = zM[s], sgs = sM[s];
    float delta = (s < STOT-1) ? (zM[s+1] - zs) : sdist;
    float d = delta*sgs;
    float tot;
    float S = block_excl_scan(d, sws, s, tot);
    wL[s] = (1.f - __expf(-d)) * __expf(-S);
  }
  LGKM0();   // wL/zM/oidM reads below are wave-local; cross-wave covered by scan syncs

  // ---------- render: color MLP only, geo gathered from passes ----------
  float accR=0.f, accG=0.f, accB=0.f, accW=0.f;
  #pragma unroll
  for(int g=0; g<4; g++){
    const int sidx = wv*64 + g*16 + c;
    float x=0.f, y=0.f, zz=0.f;
    if ((q&1)==0){
      float zq = zM[sidx];     // q0 & q2 same address -> broadcast
      x = clip1(fmaf(dx,zq,ox)); y = clip1(fmaf(dy,zq,oy)); zz = clip1(fmaf(dz,zq,oz));
    }
    short8 bcf = (short8){0,0,0,0,0,0,0,0};
    if (q < 2){
      int oid = (int)oidM[sidx];                      // q0/q1 broadcast
      bcf = *(const short8*)&GeoAll[oid*16 + q*8];    // k0..15: [od0(dead), geo0..14]
    } else if (q == 2){
      unsigned int* bu = (unsigned int*)&bcf;         // k16..21 = pos/dir
      bu[0] = pk2bf(x,y); bu[1] = pk2bf(zz,dx); bu[2] = pk2bf(dy,dz); bu[3] = 0u;
    }
    float4_ acc;
    #pragma unroll
    for(int t=0;t<4;t++){
      acc = bc1v[t];
      acc = __builtin_amdgcn_mfma_f32_16x16x32_bf16(aWc1T[t], bcf, acc, 0,0,0);
      unsigned long long dd =
          (unsigned long long)pk2bf(fmaxf(acc[0],0.f), fmaxf(acc[1],0.f))
        | ((unsigned long long)pk2bf(fmaxf(acc[2],0.f), fmaxf(acc[3],0.f))<<32);
      *(unsigned long long*)&Hw[hbase + t*256] = dd;
    }
    LGKM0();
    short8 h0 = *(const short8*)&Hw[lread];
    short8 h1 = *(const short8*)&Hw[512 + lread];
    float4_ oc = bTc;
    oc = __builtin_amdgcn_mfma_f32_16x16x32_bf16(aWc2T[0], h0, oc, 0,0,0);
    oc = __builtin_amdgcn_mfma_f32_16x16x32_bf16(aWc2T[1], h1, oc, 0,0,0);
    if (q==0){
      float wgt = wL[sidx];
      if (wgt > 1e-4f){
        accR = fmaf(wgt, sigmoidf_(oc[0]), accR);
        accG = fmaf(wgt, sigmoidf_(oc[1]), accG);
        accB = fmaf(wgt, sigmoidf_(oc[2]), accB);
      }
      accW += wgt;
    }
    LGKM0();
  }

  // ---------- reduce ----------
  #pragma unroll
  for(int off=32; off; off>>=1){
    accR += __shfl_down(accR, off, 64);
    accG += __shfl_down(accG, off, 64);
    accB += __shfl_down(accB, off, 64);
    accW += __shfl_down(accW, off, 64);
  }
  if (lane == 0){ red[wv*4+0]=accR; red[wv*4+1]=accG; red[wv*4+2]=accB; red[wv*4+3]=accW; }
  __syncthreads();
  if (s == 0){
    float R=0.f,G=0.f,B=0.f,W=0.f;
    #pragma unroll
    for(int k=0;k<4;k++){ R+=red[k*4+0]; G+=red[k*4+1]; B+=red[k*4+2]; W+=red[k*4+3]; }
    float bg = 1.f - W;
    out[r*3+0] = R + bg;
    out[r*3+1] = G + bg;
    out[r*3+2] = B + bg;
  }
}

extern "C" void kernel_launch(void* const* d_in, const int* in_sizes, int n_in,
                              void* d_out, int out_size, void* d_ws, size_t ws_size,
                              hipStream_t stream) {
  const float* ro  = (const float*)d_in[0];
  const float* rd  = (const float*)d_in[1];
  const float* W1  = (const float*)d_in[2];
  const float* b1  = (const float*)d_in[3];
  const float* W2  = (const float*)d_in[4];
  const float* b2  = (const float*)d_in[5];
  const float* Wc1 = (const float*)d_in[6];
  const float* bc1 = (const float*)d_in[7];
  const float* Wc2 = (const float*)d_in[8];
  const float* bc2 = (const float*)d_in[9];
  float* out = (float*)d_out;

  unsigned short* wb = (unsigned short*)d_ws;   // 6144 bf16 fragment words

  prep_weights<<<dim3(24), dim3(256), 0, stream>>>(W1, W2, Wc1, Wc2, wb);
  nerf_fused<<<dim3(NRAYS), dim3(256), 0, stream>>>(
      ro, rd, b1, b2, bc1, bc2, wb, out);
}

// Round 9
// 253.831 us; speedup vs baseline: 1.4181x; 1.1100x over previous
//
#include <hip/hip_runtime.h>
#include <hip/hip_fp16.h>
#include <math.h>

#define NRAYS 16384
#define HID 64
#define NS 128
#define NUP 128
#define STOT 256

typedef float    float4_ __attribute__((ext_vector_type(4)));
typedef _Float16 half8   __attribute__((ext_vector_type(8)));
typedef __fp16   fp16x2  __attribute__((ext_vector_type(2)));

#define LGKM0() __asm__ __volatile__("s_waitcnt lgkmcnt(0)" ::: "memory")

__device__ __forceinline__ float clip1(float v){ return fminf(fmaxf(v,-1.f),1.f); }
__device__ __forceinline__ float softplusf_(float x){
  return fmaxf(x,0.f) + __logf(1.f + __expf(-fabsf(x)));
}
__device__ __forceinline__ float sigmoidf_(float x){
  return __fdividef(1.f, 1.f + __expf(-x));
}

// 1-inst HW pack: 2 floats -> 2 f16 (RTZ). a -> low16, b -> high16.
__device__ __forceinline__ unsigned int pkh(float a, float b){
  union { fp16x2 h; unsigned int u; } cv;
  cv.h = __builtin_amdgcn_cvt_pkrtz(a, b);
  return cv.u;
}
__device__ __forceinline__ unsigned long long pk64(float4_ a){
  return (unsigned long long)pkh(a[0],a[1]) | ((unsigned long long)pkh(a[2],a[3])<<32);
}

__device__ __forceinline__ void load_ray(const float* ro, const float* rd, int r,
    float& ox,float& oy,float& oz,float& dx,float& dy,float& dz){
  ox=ro[3*r]; oy=ro[3*r+1]; oz=ro[3*r+2];
  dx=rd[3*r]; dy=rd[3*r+1]; dz=rd[3*r+2];
  float inv = 1.f/sqrtf(dx*dx+dy*dy+dz*dz);
  dx*=inv; dy*=inv; dz*=inv;
}

__device__ __forceinline__ void aabb_nf(float ox,float oy,float oz,float dx,float dy,float dz,
    float& nears,float& fars){
  float dsx = (fabsf(dx)<1e-8f)?1e-8f:dx;
  float dsy = (fabsf(dy)<1e-8f)?1e-8f:dy;
  float dsz = (fabsf(dz)<1e-8f)?1e-8f:dz;
  float t1x=(-1.f-ox)/dsx, t2x=(1.f-ox)/dsx;
  float t1y=(-1.f-oy)/dsy, t2y=(1.f-oy)/dsy;
  float t1z=(-1.f-oz)/dsz, t2z=(1.f-oz)/dsz;
  float nr = fmaxf(fmaxf(fminf(t1x,t2x),fminf(t1y,t2y)),fminf(t1z,t2z));
  float fr = fminf(fminf(fmaxf(t1x,t2x),fmaxf(t1y,t2y)),fmaxf(t1z,t2z));
  fars  = fmaxf(fminf(fr,5.f),0.2f);
  nears = fminf(fmaxf(nr,0.2f),5.f);
}

// exclusive block scan over 256 threads / 4 waves (contains __syncthreads)
__device__ __forceinline__ float block_excl_scan(float v, float* lds_ws,
    int tid, float& total){
  float incl = v;
  #pragma unroll
  for(int off=1; off<64; off<<=1){
    float n = __shfl_up(incl, off, 64);
    if ((tid & 63) >= off) incl += n;
  }
  int wv = tid >> 6;
  if ((tid & 63) == 63) lds_ws[wv] = incl;
  __syncthreads();
  float woff = 0.f, tot = 0.f;
  #pragma unroll
  for(int k=0;k<4;k++){ float s = lds_ws[k]; tot += s; if (k < wv) woff += s; }
  __syncthreads();
  total = tot;
  return woff + incl - v;
}

// ---------------- weight prep: f16 A-fragments (transposed weights) ----------------
// A-frag: lane l holds A[m=l&15][k=(l>>4)*8+j]. 12 slots of 64 lanes x 8 halves:
// slots 0..3 : W1^T  (M-tile mt: m=h=mt*16+c):  A = W1[k][h], k>=3 -> 0
// slots 4..5 : W2^T  (K-step ks: k=h=ks*32+..): A = W2[h][od=c]
// slots 6..9 : Wc1^T (M-tile mt), PERMUTED k:   k=0 -> 0 row (od0=sigma unused);
//              k in 1..15 -> geo_{k-1} (Wc1 row 5+k); k in 16..21 -> pos/dir
//              (Wc1 row k-16); k>=22 -> 0
// slots 10..11: Wc2^T: A = (c<3)? Wc2[h][c] : 0
__global__ void prep_weights(const float* __restrict__ W1, const float* __restrict__ W2,
                             const float* __restrict__ Wc1, const float* __restrict__ Wc2,
                             unsigned short* __restrict__ wb){
  int idx = blockIdx.x*256 + threadIdx.x;
  if (idx >= 6144) return;
  int f = idx>>3, j = idx&7, lane = f&63, slot = f>>6, q = lane>>4, c = lane&15;
  int k = q*8+j;
  float v = 0.f;
  if (slot < 4){        if (k<3) v = W1[k*HID + slot*16 + c]; }
  else if (slot < 6){   int h=(slot-4)*32+k; v = W2[h*16 + c]; }
  else if (slot < 10){  int mt=slot-6;
                        int row = (k==0)? -1 : (k<16 ? 5+k : (k<22 ? k-16 : -1));
                        if (row>=0) v = Wc1[row*HID + mt*16 + c]; }
  else {                int h=(slot-10)*32+k; if (c<3) v = Wc2[h*3 + c]; }
  wb[idx] = __half_as_ushort(__float2half_rn(v));
}

// relu + pack a layer-1 C-tile (4 h-rows, sample c) -> one b64 into frag-major H
__device__ __forceinline__ void storeH(unsigned short* H, float4_ a, int t, int hbase){
  unsigned long long dd =
      (unsigned long long)pkh(fmaxf(a[0],0.f), fmaxf(a[1],0.f))
    | ((unsigned long long)pkh(fmaxf(a[2],0.f), fmaxf(a[3],0.f))<<32);
  *(unsigned long long*)&H[hbase + t*256] = dd;
}

// ================= fully fused NeRF kernel: 256 threads / ray-block =================
__global__ __launch_bounds__(256) void nerf_fused(
    const float* __restrict__ ro, const float* __restrict__ rd,
    const float* __restrict__ b1, const float* __restrict__ b2,
    const float* __restrict__ bc1, const float* __restrict__ bc2,
    const unsigned short* __restrict__ wb, float* __restrict__ out)
{
  __shared__ __align__(16) unsigned short Hfrag[4][2][1024]; // 16 KB (2 bufs/wave)
  __shared__ __align__(16) unsigned short GeoAll[256*16];    // 8 KB: od0..15 per sample
  __shared__ float sigC[128], sigF[128], newzL[128], cdf[128], zBs[128];
  __shared__ float zM[257], sM[256], wL[256];
  __shared__ unsigned short oidM[256];
  __shared__ float sws[4], red[16];

  const int r = blockIdx.x;
  const int s = threadIdx.x, lane = s&63, wv = s>>6;
  const int q = lane>>4, c = lane&15;

  float ox,oy,oz,dx,dy,dz;
  load_ray(ro,rd,r,ox,oy,oz,dx,dy,dz);
  float nears,fars; aabb_nf(ox,oy,oz,dx,dy,dz,nears,fars);
  const float step  = (fars-nears)*(1.f/127.f);
  const float sdist = (fars-nears)*(1.f/128.f);
  const bool asc = (nears <= fars);

  const half8* WF = (const half8*)wb;
  half8 aW1T[4], aW2T[2], aWc1T[4], aWc2T[2];
  #pragma unroll
  for(int t=0;t<4;t++){ aW1T[t] = WF[t*64+lane]; aWc1T[t] = WF[(6+t)*64+lane]; }
  #pragma unroll
  for(int k=0;k<2;k++){ aW2T[k] = WF[(4+k)*64+lane]; aWc2T[k] = WF[(10+k)*64+lane]; }
  float4_ b1v[4], bc1v[4];
  #pragma unroll
  for(int t=0;t<4;t++){
    b1v[t]  = *(const float4_*)&b1[t*16+q*4];
    bc1v[t] = *(const float4_*)&bc1[t*16+q*4];
  }
  const float4_ bTd = *(const float4_*)&b2[q*4];
  float4_ bTc = (float4_){0.f,0.f,0.f,0.f};
  if (q==0){ bTc[0]=bc2[0]; bTc[1]=bc2[1]; bTc[2]=bc2[2]; }

  unsigned short* H0 = &Hfrag[wv][0][0];
  unsigned short* H1 = &Hfrag[wv][1][0];
  const int hbase = (q>>1)*128 + c*8 + (q&1)*4;   // ushort index (writer)
  const int lread = lane*8;                        // ushort index (reader)

  // ---------- coarse (pass 0) + pdf + fine (pass 1), pair-interleaved ----------
  for(int pass=0; pass<2; pass++){
    if (pass==1){
      // pdf from coarse sigmas; exp-space scan of d_i = step*sigma_i
      float d = (s<127) ? step * sigC[s] : 0.f;
      float tot;
      float S = block_excl_scan(d, sws, s, tot);
      float w = (s<127) ? (1.f - __expf(-d)) * __expf(-S) : 0.f;
      float ww = (s>=1 && s<127) ? (w + 1e-5f) : 0.f;
      float wsum;
      float ce = block_excl_scan(ww, sws, s, wsum);
      if (s<127) cdf[s] = __fdividef(ce+ww, wsum);
      __syncthreads();
      if (s<128){
        const float u0 = 0.5f/128.f;
        const float du = (1.f - 1.f/128.f)/127.f;
        float u = u0 + du*(float)s;
        // two-level fanout search: lo = #{m in [0,127): cdf[m] <= u}
        int b = 0;
        #pragma unroll
        for(int k=0;k<7;k++) b += (cdf[16*k+15] <= u) ? 1 : 0;
        int rc = 0;
        #pragma unroll
        for(int j=0;j<15;j++) rc += (cdf[16*b+j] <= u) ? 1 : 0;
        int lo = 16*b + rc;
        int below = max(lo-1,0), above = min(lo,126);
        float c0 = cdf[below], c1 = cdf[above];
        float bb0 = nears + step*((float)below + 0.5f);
        float bb1 = nears + step*((float)above + 0.5f);
        float den = c1 - c0; if (den < 1e-5f) den = 1.f;
        float zf = bb0 + (u - c0)/den*(bb1 - bb0);
        newzL[s] = zf;
        zBs[asc ? s : 127-s] = zf;   // ascending-sorted fine list
      }
      __syncthreads();
    }

    // this wave's 32 samples as one interleaved pair of 16-sample groups
    {
      const int sidx0 = wv*32 + c;
      const int sidx1 = wv*32 + 16 + c;
      half8 bf0 = (half8)(_Float16)0, bf1 = (half8)(_Float16)0;
      if (q==0){
        float z0 = pass ? newzL[sidx0] : fmaf(step,(float)sidx0,nears);
        float z1 = pass ? newzL[sidx1] : fmaf(step,(float)sidx1,nears);
        unsigned int* u0p = (unsigned int*)&bf0;
        u0p[0] = pkh(clip1(fmaf(dx,z0,ox)), clip1(fmaf(dy,z0,oy)));
        u0p[1] = pkh(clip1(fmaf(dz,z0,oz)), 0.f);
        unsigned int* u1p = (unsigned int*)&bf1;
        u1p[0] = pkh(clip1(fmaf(dx,z1,ox)), clip1(fmaf(dy,z1,oy)));
        u1p[1] = pkh(clip1(fmaf(dz,z1,oz)), 0.f);
      }
      #pragma unroll
      for(int t=0;t<4;t++){
        float4_ a0 = __builtin_amdgcn_mfma_f32_16x16x32_f16(aW1T[t], bf0, b1v[t], 0,0,0);
        float4_ a1 = __builtin_amdgcn_mfma_f32_16x16x32_f16(aW1T[t], bf1, b1v[t], 0,0,0);
        storeH(H0, a0, t, hbase);
        storeH(H1, a1, t, hbase);
      }
      LGKM0();
      half8 h00 = *(const half8*)&H0[lread];
      half8 h01 = *(const half8*)&H0[512 + lread];
      half8 h10 = *(const half8*)&H1[lread];
      half8 h11 = *(const half8*)&H1[512 + lread];
      float4_ o0 = __builtin_amdgcn_mfma_f32_16x16x32_f16(aW2T[0], h00, bTd, 0,0,0);
      o0 = __builtin_amdgcn_mfma_f32_16x16x32_f16(aW2T[1], h01, o0, 0,0,0);
      float4_ o1 = __builtin_amdgcn_mfma_f32_16x16x32_f16(aW2T[0], h10, bTd, 0,0,0);
      o1 = __builtin_amdgcn_mfma_f32_16x16x32_f16(aW2T[1], h11, o1, 0,0,0);
      // full od tile (sigma + geo, raw) -> GeoAll[sample][q*4..q*4+3]
      *(unsigned long long*)&GeoAll[(pass*128 + sidx0)*16 + q*4] = pk64(o0);
      *(unsigned long long*)&GeoAll[(pass*128 + sidx1)*16 + q*4] = pk64(o1);
      if (q==0){
        float* sg = pass ? sigF : sigC;
        sg[sidx0] = softplusf_(o0[0]);
        sg[sidx1] = softplusf_(o1[0]);
      }
    }
    __syncthreads();
  }

  // ---------- merge (coarse grid is linear -> computed / fanout searches) ----------
  {
    float myz, mysig; int pos, oid;
    if (s < 128){
      int i = asc ? s : 127-s;
      myz = fmaf(step, (float)i, nears);
      mysig = sigC[i];
      oid = i;
      // two-level fanout: lo = #{m in [0,128): zBs[m] < myz}
      int b = 0;
      #pragma unroll
      for(int k=0;k<7;k++) b += (zBs[16*k+15] < myz) ? 1 : 0;
      int rc = 0;
      #pragma unroll
      for(int j=0;j<16;j++) rc += (zBs[16*b+j] < myz) ? 1 : 0;
      pos = s + 16*b + rc;
    } else {
      int k = s-128;
      myz = zBs[k];
      int fo = asc ? k : 127-k;
      mysig = sigF[fo];
      oid = 128 + fo;
      int lo=0, hi=128;        // register-only binary search over computed coarse z
      while(lo<hi){
        int m=(lo+hi)>>1;
        float Am = fmaf(step, (float)(asc ? m : 127-m), nears);
        if (Am <= myz) lo=m+1; else hi=m;
      }
      pos = k + lo;
    }
    zM[pos]=myz; sM[pos]=mysig; oidM[pos]=(unsigned short)oid;
    __syncthreads();
  }

  // ---------- composite (exp-space scan) ----------
  {
    float zs = zM[s], sgs = sM[s];
    float delta = (s < STOT-1) ? (zM[s+1] - zs) : sdist;
    float d = delta*sgs;
    float tot;
    float S = block_excl_scan(d, sws, s, tot);
    wL[s] = (1.f - __expf(-d)) * __expf(-S);
  }
  LGKM0();

  // ---------- render: color MLP only (geo gathered), pair-interleaved ----------
  float accR=0.f, accG=0.f, accB=0.f, accW=0.f;
  #pragma unroll
  for(int p=0;p<2;p++){
    const int sidx0 = wv*64 + (2*p)*16 + c;
    const int sidx1 = wv*64 + (2*p+1)*16 + c;
    float z0 = zM[sidx0], z1 = zM[sidx1];
    float x0 = clip1(fmaf(dx,z0,ox)), y0 = clip1(fmaf(dy,z0,oy)), w0 = clip1(fmaf(dz,z0,oz));
    float x1 = clip1(fmaf(dx,z1,ox)), y1 = clip1(fmaf(dy,z1,oy)), w1 = clip1(fmaf(dz,z1,oz));
    half8 bcf0 = (half8)(_Float16)0, bcf1 = (half8)(_Float16)0;
    if (q < 2){
      int o0i = (int)oidM[sidx0];
      int o1i = (int)oidM[sidx1];
      bcf0 = *(const half8*)&GeoAll[o0i*16 + q*8];   // k0..15: [od0(dead), geo0..14]
      bcf1 = *(const half8*)&GeoAll[o1i*16 + q*8];
    } else if (q == 2){
      unsigned int* u0p = (unsigned int*)&bcf0;      // k16..21 = pos/dir
      u0p[0] = pkh(x0,y0); u0p[1] = pkh(w0,dx); u0p[2] = pkh(dy,dz); u0p[3] = 0u;
      unsigned int* u1p = (unsigned int*)&bcf1;
      u1p[0] = pkh(x1,y1); u1p[1] = pkh(w1,dx); u1p[2] = pkh(dy,dz); u1p[3] = 0u;
    }
    #pragma unroll
    for(int t=0;t<4;t++){
      float4_ a0 = __builtin_amdgcn_mfma_f32_16x16x32_f16(aWc1T[t], bcf0, bc1v[t], 0,0,0);
      float4_ a1 = __builtin_amdgcn_mfma_f32_16x16x32_f16(aWc1T[t], bcf1, bc1v[t], 0,0,0);
      storeH(H0, a0, t, hbase);
      storeH(H1, a1, t, hbase);
    }
    LGKM0();
    half8 h00 = *(const half8*)&H0[lread];
    half8 h01 = *(const half8*)&H0[512 + lread];
    half8 h10 = *(const half8*)&H1[lread];
    half8 h11 = *(const half8*)&H1[512 + lread];
    float4_ oc0 = __builtin_amdgcn_mfma_f32_16x16x32_f16(aWc2T[0], h00, bTc, 0,0,0);
    oc0 = __builtin_amdgcn_mfma_f32_16x16x32_f16(aWc2T[1], h01, oc0, 0,0,0);
    float4_ oc1 = __builtin_amdgcn_mfma_f32_16x16x32_f16(aWc2T[0], h10, bTc, 0,0,0);
    oc1 = __builtin_amdgcn_mfma_f32_16x16x32_f16(aWc2T[1], h11, oc1, 0,0,0);
    if (q==0){
      float g0w = wL[sidx0];
      if (g0w > 1e-4f){
        accR = fmaf(g0w, sigmoidf_(oc0[0]), accR);
        accG = fmaf(g0w, sigmoidf_(oc0[1]), accG);
        accB = fmaf(g0w, sigmoidf_(oc0[2]), accB);
      }
      accW += g0w;
      float g1w = wL[sidx1];
      if (g1w > 1e-4f){
        accR = fmaf(g1w, sigmoidf_(oc1[0]), accR);
        accG = fmaf(g1w, sigmoidf_(oc1[1]), accG);
        accB = fmaf(g1w, sigmoidf_(oc1[2]), accB);
      }
      accW += g1w;
    }
    LGKM0();   // WAR guard: H bufs reused by next pair
  }

  // ---------- reduce ----------
  #pragma unroll
  for(int off=32; off; off>>=1){
    accR += __shfl_down(accR, off, 64);
    accG += __shfl_down(accG, off, 64);
    accB += __shfl_down(accB, off, 64);
    accW += __shfl_down(accW, off, 64);
  }
  if (lane == 0){ red[wv*4+0]=accR; red[wv*4+1]=accG; red[wv*4+2]=accB; red[wv*4+3]=accW; }
  __syncthreads();
  if (s == 0){
    float R=0.f,G=0.f,B=0.f,W=0.f;
    #pragma unroll
    for(int k=0;k<4;k++){ R+=red[k*4+0]; G+=red[k*4+1]; B+=red[k*4+2]; W+=red[k*4+3]; }
    float bg = 1.f - W;
    out[r*3+0] = R + bg;
    out[r*3+1] = G + bg;
    out[r*3+2] = B + bg;
  }
}

extern "C" void kernel_launch(void* const* d_in, const int* in_sizes, int n_in,
                              void* d_out, int out_size, void* d_ws, size_t ws_size,
                              hipStream_t stream) {
  const float* ro  = (const float*)d_in[0];
  const float* rd  = (const float*)d_in[1];
  const float* W1  = (const float*)d_in[2];
  const float* b1  = (const float*)d_in[3];
  const float* W2  = (const float*)d_in[4];
  const float* b2  = (const float*)d_in[5];
  const float* Wc1 = (const float*)d_in[6];
  const float* bc1 = (const float*)d_in[7];
  const float* Wc2 = (const float*)d_in[8];
  const float* bc2 = (const float*)d_in[9];
  float* out = (float*)d_out;

  unsigned short* wb = (unsigned short*)d_ws;   // 6144 f16 fragment words

  prep_weights<<<dim3(24), dim3(256), 0, stream>>>(W1, W2, Wc1, Wc2, wb);
  nerf_fused<<<dim3(NRAYS), dim3(256), 0, stream>>>(
      ro, rd, b1, b2, bc1, bc2, wb, out);
}

// Round 10
// 230.087 us; speedup vs baseline: 1.5645x; 1.1032x over previous
//
#include <hip/hip_runtime.h>
#include <hip/hip_fp16.h>
#include <math.h>

#define NRAYS 16384
#define HID 64
#define NS 128
#define NUP 128
#define STOT 256

typedef float    float4_ __attribute__((ext_vector_type(4)));
typedef float    float2_ __attribute__((ext_vector_type(2)));
typedef _Float16 half8   __attribute__((ext_vector_type(8)));
typedef __fp16   fp16x2  __attribute__((ext_vector_type(2)));

#define LGKM0() __asm__ __volatile__("s_waitcnt lgkmcnt(0)" ::: "memory")

__device__ __forceinline__ float clip1(float v){ return fminf(fmaxf(v,-1.f),1.f); }
__device__ __forceinline__ float softplusf_(float x){
  return fmaxf(x,0.f) + __logf(1.f + __expf(-fabsf(x)));
}
__device__ __forceinline__ float sigmoidf_(float x){
  return __fdividef(1.f, 1.f + __expf(-x));
}

// 1-inst HW pack: 2 floats -> 2 f16 (RTZ). a -> low16, b -> high16.
__device__ __forceinline__ unsigned int pkh(float a, float b){
  union { fp16x2 h; unsigned int u; } cv;
  cv.h = __builtin_amdgcn_cvt_pkrtz(a, b);
  return cv.u;
}
__device__ __forceinline__ unsigned long long pk64(float4_ a){
  return (unsigned long long)pkh(a[0],a[1]) | ((unsigned long long)pkh(a[2],a[3])<<32);
}

__device__ __forceinline__ void load_ray(const float* ro, const float* rd, int r,
    float& ox,float& oy,float& oz,float& dx,float& dy,float& dz){
  ox=ro[3*r]; oy=ro[3*r+1]; oz=ro[3*r+2];
  dx=rd[3*r]; dy=rd[3*r+1]; dz=rd[3*r+2];
  float inv = 1.f/sqrtf(dx*dx+dy*dy+dz*dz);
  dx*=inv; dy*=inv; dz*=inv;
}

__device__ __forceinline__ void aabb_nf(float ox,float oy,float oz,float dx,float dy,float dz,
    float& nears,float& fars){
  float dsx = (fabsf(dx)<1e-8f)?1e-8f:dx;
  float dsy = (fabsf(dy)<1e-8f)?1e-8f:dy;
  float dsz = (fabsf(dz)<1e-8f)?1e-8f:dz;
  float t1x=(-1.f-ox)/dsx, t2x=(1.f-ox)/dsx;
  float t1y=(-1.f-oy)/dsy, t2y=(1.f-oy)/dsy;
  float t1z=(-1.f-oz)/dsz, t2z=(1.f-oz)/dsz;
  float nr = fmaxf(fmaxf(fminf(t1x,t2x),fminf(t1y,t2y)),fminf(t1z,t2z));
  float fr = fminf(fminf(fmaxf(t1x,t2x),fmaxf(t1y,t2y)),fmaxf(t1z,t2z));
  fars  = fmaxf(fminf(fr,5.f),0.2f);
  nears = fminf(fmaxf(nr,0.2f),5.f);
}

// wave-level exclusive scan over per-lane chunk sums; no barriers.
__device__ __forceinline__ float wave_excl_chunk(float chunk, int lane, float& total){
  float incl = chunk;
  #pragma unroll
  for(int off=1; off<64; off<<=1){
    float n = __shfl_up(incl, off, 64);
    if (lane >= off) incl += n;
  }
  total = __shfl(incl, 63, 64);
  return incl - chunk;
}

// ---------------- weight prep: f16 A-fragments (transposed weights) ----------------
// A-frag: lane l holds A[m=l&15][k=(l>>4)*8+j]. 12 slots of 64 lanes x 8 halves:
// slots 0..3 : W1^T  (M-tile mt: m=h=mt*16+c):  A = W1[k][h], k>=3 -> 0
// slots 4..5 : W2^T  (K-step ks: k=h=ks*32+..): A = W2[h][od=c]
// slots 6..9 : Wc1^T (M-tile mt), PERMUTED k:   k=0 -> 0 row (od0=sigma unused);
//              k in 1..15 -> geo_{k-1} (Wc1 row 5+k); k in 16..21 -> pos/dir
//              (Wc1 row k-16); k>=22 -> 0
// slots 10..11: Wc2^T: A = (c<3)? Wc2[h][c] : 0
__global__ void prep_weights(const float* __restrict__ W1, const float* __restrict__ W2,
                             const float* __restrict__ Wc1, const float* __restrict__ Wc2,
                             unsigned short* __restrict__ wb){
  int idx = blockIdx.x*256 + threadIdx.x;
  if (idx >= 6144) return;
  int f = idx>>3, j = idx&7, lane = f&63, slot = f>>6, q = lane>>4, c = lane&15;
  int k = q*8+j;
  float v = 0.f;
  if (slot < 4){        if (k<3) v = W1[k*HID + slot*16 + c]; }
  else if (slot < 6){   int h=(slot-4)*32+k; v = W2[h*16 + c]; }
  else if (slot < 10){  int mt=slot-6;
                        int row = (k==0)? -1 : (k<16 ? 5+k : (k<22 ? k-16 : -1));
                        if (row>=0) v = Wc1[row*HID + mt*16 + c]; }
  else {                int h=(slot-10)*32+k; if (c<3) v = Wc2[h*3 + c]; }
  wb[idx] = __half_as_ushort(__float2half_rn(v));
}

// relu + pack a layer-1 C-tile (4 h-rows, sample c) -> one b64 into frag-major H
__device__ __forceinline__ void storeH(unsigned short* H, float4_ a, int t, int hbase){
  unsigned long long dd =
      (unsigned long long)pkh(fmaxf(a[0],0.f), fmaxf(a[1],0.f))
    | ((unsigned long long)pkh(fmaxf(a[2],0.f), fmaxf(a[3],0.f))<<32);
  *(unsigned long long*)&H[hbase + t*256] = dd;
}

// ========== fully fused NeRF: 1 WAVE per ray, 4 rays/block, ZERO __syncthreads ==========
__global__ __launch_bounds__(256) void nerf_fused(
    const float* __restrict__ ro, const float* __restrict__ rd,
    const float* __restrict__ b1, const float* __restrict__ b2,
    const float* __restrict__ bc1, const float* __restrict__ bc2,
    const unsigned short* __restrict__ wb, float* __restrict__ out)
{
  // per-wave private LDS slices (no cross-wave sharing anywhere)
  __shared__ __align__(16) unsigned short Hfrag[4][2][1024];  // 16 KB
  __shared__ __align__(16) unsigned short GeoAll[4][256*16];  // 32 KB
  __shared__ __align__(16) float sigC[4][128];                // 2 KB
  __shared__ __align__(16) float sigF[4][128];                // 2 KB
  __shared__ __align__(16) float zBs[4][128];                 // 2 KB
  __shared__ __align__(16) float cdf[4][128];                 // 2 KB
  __shared__ __align__(16) float zM[4][260];                  // ~4 KB
  __shared__ __align__(16) float sM[4][256];                  // 4 KB
  __shared__ __align__(16) float wL[4][256];                  // 4 KB
  __shared__ unsigned short oidM[4][256];                     // 2 KB

  const int tid = threadIdx.x, lane = tid&63, wv = tid>>6;
  const int q = lane>>4, c = lane&15;
  const int r = blockIdx.x*4 + wv;

  float ox,oy,oz,dx,dy,dz;
  load_ray(ro,rd,r,ox,oy,oz,dx,dy,dz);
  float nears,fars; aabb_nf(ox,oy,oz,dx,dy,dz,nears,fars);
  const float step  = (fars-nears)*(1.f/127.f);
  const float sdist = (fars-nears)*(1.f/128.f);
  const bool asc = (nears <= fars);

  const half8* WF = (const half8*)wb;
  half8 aW1T[4], aW2T[2], aWc1T[4], aWc2T[2];
  #pragma unroll
  for(int t=0;t<4;t++){ aW1T[t] = WF[t*64+lane]; aWc1T[t] = WF[(6+t)*64+lane]; }
  #pragma unroll
  for(int k=0;k<2;k++){ aW2T[k] = WF[(4+k)*64+lane]; aWc2T[k] = WF[(10+k)*64+lane]; }
  float4_ b1v[4], bc1v[4];
  #pragma unroll
  for(int t=0;t<4;t++){
    b1v[t]  = *(const float4_*)&b1[t*16+q*4];
    bc1v[t] = *(const float4_*)&bc1[t*16+q*4];
  }
  const float4_ bTd = *(const float4_*)&b2[q*4];
  float4_ bTc = (float4_){0.f,0.f,0.f,0.f};
  if (q==0){ bTc[0]=bc2[0]; bTc[1]=bc2[1]; bTc[2]=bc2[2]; }

  unsigned short* H0 = &Hfrag[wv][0][0];
  unsigned short* H1 = &Hfrag[wv][1][0];
  unsigned short* Geo = &GeoAll[wv][0];
  float* sigCw = sigC[wv]; float* sigFw = sigF[wv];
  float* zBsw = zBs[wv];   float* cdfw = cdf[wv];
  float* zMw = zM[wv];     float* sMw = sM[wv];  float* wLw = wL[wv];
  unsigned short* oidw = oidM[wv];
  const int hbase = (q>>1)*128 + c*8 + (q&1)*4;   // ushort index (writer)
  const int lread = lane*8;                        // ushort index (reader)

  // ---------- pass 0: coarse density (8 groups, pair-interleaved) ----------
  #pragma unroll
  for(int p=0;p<4;p++){
    const int sidx0 = p*32 + c, sidx1 = p*32 + 16 + c;
    half8 bf0 = (half8)(_Float16)0, bf1 = (half8)(_Float16)0;
    if (q==0){
      float z0 = fmaf(step,(float)sidx0,nears);
      float z1 = fmaf(step,(float)sidx1,nears);
      unsigned int* u0p = (unsigned int*)&bf0;
      u0p[0] = pkh(clip1(fmaf(dx,z0,ox)), clip1(fmaf(dy,z0,oy)));
      u0p[1] = pkh(clip1(fmaf(dz,z0,oz)), 0.f);
      unsigned int* u1p = (unsigned int*)&bf1;
      u1p[0] = pkh(clip1(fmaf(dx,z1,ox)), clip1(fmaf(dy,z1,oy)));
      u1p[1] = pkh(clip1(fmaf(dz,z1,oz)), 0.f);
    }
    #pragma unroll
    for(int t=0;t<4;t++){
      float4_ a0 = __builtin_amdgcn_mfma_f32_16x16x32_f16(aW1T[t], bf0, b1v[t], 0,0,0);
      float4_ a1 = __builtin_amdgcn_mfma_f32_16x16x32_f16(aW1T[t], bf1, b1v[t], 0,0,0);
      storeH(H0, a0, t, hbase);
      storeH(H1, a1, t, hbase);
    }
    LGKM0();
    half8 h00 = *(const half8*)&H0[lread];
    half8 h01 = *(const half8*)&H0[512 + lread];
    half8 h10 = *(const half8*)&H1[lread];
    half8 h11 = *(const half8*)&H1[512 + lread];
    float4_ o0 = __builtin_amdgcn_mfma_f32_16x16x32_f16(aW2T[0], h00, bTd, 0,0,0);
    o0 = __builtin_amdgcn_mfma_f32_16x16x32_f16(aW2T[1], h01, o0, 0,0,0);
    float4_ o1 = __builtin_amdgcn_mfma_f32_16x16x32_f16(aW2T[0], h10, bTd, 0,0,0);
    o1 = __builtin_amdgcn_mfma_f32_16x16x32_f16(aW2T[1], h11, o1, 0,0,0);
    *(unsigned long long*)&Geo[sidx0*16 + q*4] = pk64(o0);
    *(unsigned long long*)&Geo[sidx1*16 + q*4] = pk64(o1);
    if (q==0){ sigCw[sidx0] = softplusf_(o0[0]); sigCw[sidx1] = softplusf_(o1[0]); }
    LGKM0();   // WAR guard before H reuse
  }

  // ---------- pdf: wave-local exp-space scan + cdf (2 elems/lane) ----------
  {
    float2_ sg = *(const float2_*)&sigCw[2*lane];
    float d0 = (2*lane   < 127) ? step*sg[0] : 0.f;
    float d1 = (2*lane+1 < 127) ? step*sg[1] : 0.f;
    float tot;
    float e0 = wave_excl_chunk(d0+d1, lane, tot);
    float w0 = (1.f-__expf(-d0))*__expf(-e0);
    float w1 = (1.f-__expf(-d1))*__expf(-(e0+d0));
    float ww0 = (lane>=1 && 2*lane<127) ? w0+1e-5f : ((lane==0)?0.f:0.f);
    if (lane==0) ww0 = 0.f;                         // i=0 excluded
    else if (2*lane>=127) ww0 = 0.f;
    float ww1 = (2*lane+1 < 127) ? w1+1e-5f : 0.f;  // i=2l+1>=1 always
    float wsum;
    float ce0 = wave_excl_chunk(ww0+ww1, lane, wsum);
    float inv = __fdividef(1.f, wsum);
    float2_ cd;
    cd[0] = (ce0+ww0)*inv;
    cd[1] = (ce0+ww0+ww1)*inv;
    *(float2_*)&cdfw[2*lane] = cd;                  // cdf[127] written, never read
  }
  LGKM0();

  // ---------- inverse-CDF sampling (2 fine samples/lane), stored z-sorted ----------
  {
    const float u0c = 0.5f/128.f;
    const float du = (1.f - 1.f/128.f)/127.f;
    #pragma unroll
    for(int j=0;j<2;j++){
      int k = lane + j*64;
      float u = fmaf(du,(float)k,u0c);
      int lo=0, hi=127;
      while(lo<hi){ int m=(lo+hi)>>1; if (cdfw[m] <= u) lo=m+1; else hi=m; }
      int below = max(lo-1,0), above = min(lo,126);
      float c0 = cdfw[below], c1 = cdfw[above];
      float bb0 = nears + step*((float)below + 0.5f);
      float bb1 = nears + step*((float)above + 0.5f);
      float den = c1 - c0; if (den < 1e-5f) den = 1.f;
      float zf = bb0 + (u - c0)/den*(bb1 - bb0);
      zBsw[asc ? k : 127-k] = zf;
    }
  }
  LGKM0();

  // ---------- pass 1: fine density, processed in z-sorted order ----------
  #pragma unroll
  for(int p=0;p<4;p++){
    const int sidx0 = p*32 + c, sidx1 = p*32 + 16 + c;
    half8 bf0 = (half8)(_Float16)0, bf1 = (half8)(_Float16)0;
    if (q==0){
      float z0 = zBsw[sidx0];
      float z1 = zBsw[sidx1];
      unsigned int* u0p = (unsigned int*)&bf0;
      u0p[0] = pkh(clip1(fmaf(dx,z0,ox)), clip1(fmaf(dy,z0,oy)));
      u0p[1] = pkh(clip1(fmaf(dz,z0,oz)), 0.f);
      unsigned int* u1p = (unsigned int*)&bf1;
      u1p[0] = pkh(clip1(fmaf(dx,z1,ox)), clip1(fmaf(dy,z1,oy)));
      u1p[1] = pkh(clip1(fmaf(dz,z1,oz)), 0.f);
    }
    #pragma unroll
    for(int t=0;t<4;t++){
      float4_ a0 = __builtin_amdgcn_mfma_f32_16x16x32_f16(aW1T[t], bf0, b1v[t], 0,0,0);
      float4_ a1 = __builtin_amdgcn_mfma_f32_16x16x32_f16(aW1T[t], bf1, b1v[t], 0,0,0);
      storeH(H0, a0, t, hbase);
      storeH(H1, a1, t, hbase);
    }
    LGKM0();
    half8 h00 = *(const half8*)&H0[lread];
    half8 h01 = *(const half8*)&H0[512 + lread];
    half8 h10 = *(const half8*)&H1[lread];
    half8 h11 = *(const half8*)&H1[512 + lread];
    float4_ o0 = __builtin_amdgcn_mfma_f32_16x16x32_f16(aW2T[0], h00, bTd, 0,0,0);
    o0 = __builtin_amdgcn_mfma_f32_16x16x32_f16(aW2T[1], h01, o0, 0,0,0);
    float4_ o1 = __builtin_amdgcn_mfma_f32_16x16x32_f16(aW2T[0], h10, bTd, 0,0,0);
    o1 = __builtin_amdgcn_mfma_f32_16x16x32_f16(aW2T[1], h11, o1, 0,0,0);
    *(unsigned long long*)&Geo[(128+sidx0)*16 + q*4] = pk64(o0);
    *(unsigned long long*)&Geo[(128+sidx1)*16 + q*4] = pk64(o1);
    if (q==0){ sigFw[sidx0] = softplusf_(o0[0]); sigFw[sidx1] = softplusf_(o1[0]); }
    LGKM0();
  }

  // ---------- merge: 2 coarse + 2 fine samples per lane, binary searches ----------
  #pragma unroll
  for(int j=0;j<2;j++){
    int sA = lane + j*64;
    int i = asc ? sA : 127-sA;
    float myz = fmaf(step,(float)i,nears);
    float sg = sigCw[i];
    int lo=0, hi=128;
    while(lo<hi){ int m=(lo+hi)>>1; if (zBsw[m] < myz) lo=m+1; else hi=m; }
    int pos = sA + lo;
    zMw[pos]=myz; sMw[pos]=sg; oidw[pos]=(unsigned short)i;
  }
  #pragma unroll
  for(int j=0;j<2;j++){
    int k = lane + j*64;
    float myz = zBsw[k];
    float sg = sigFw[k];
    int lo=0, hi=128;                 // register-only search over computed coarse z
    while(lo<hi){
      int m=(lo+hi)>>1;
      float Am = fmaf(step,(float)(asc?m:127-m),nears);
      if (Am <= myz) lo=m+1; else hi=m;
    }
    int pos = k + lo;
    zMw[pos]=myz; sMw[pos]=sg; oidw[pos]=(unsigned short)(128+k);
  }
  LGKM0();

  // ---------- composite: wave-local exp-space scan (4 elems/lane) ----------
  {
    float4_ z4 = *(const float4_*)&zMw[4*lane];
    float z5 = zMw[4*lane+4];                      // lane63 reads zM[256] (unused)
    float4_ s4 = *(const float4_*)&sMw[4*lane];
    float d0 = (z4[1]-z4[0])*s4[0];
    float d1 = (z4[2]-z4[1])*s4[1];
    float d2 = (z4[3]-z4[2])*s4[2];
    float dl = (lane==63) ? sdist : (z5 - z4[3]);
    float d3 = dl*s4[3];
    float tot;
    float S = wave_excl_chunk(d0+d1+d2+d3, lane, tot);
    float4_ w4;
    w4[0] = (1.f-__expf(-d0))*__expf(-S); S += d0;
    w4[1] = (1.f-__expf(-d1))*__expf(-S); S += d1;
    w4[2] = (1.f-__expf(-d2))*__expf(-S); S += d2;
    w4[3] = (1.f-__expf(-d3))*__expf(-S);
    *(float4_*)&wLw[4*lane] = w4;
  }
  LGKM0();

  // ---------- render: color MLP only (geo gathered), 8 pair-iterations ----------
  float accR=0.f, accG=0.f, accB=0.f, accW=0.f;
  #pragma unroll
  for(int p=0;p<8;p++){
    const int sidx0 = p*32 + c, sidx1 = p*32 + 16 + c;
    float z0 = zMw[sidx0], z1 = zMw[sidx1];
    float x0 = clip1(fmaf(dx,z0,ox)), y0 = clip1(fmaf(dy,z0,oy)), w0 = clip1(fmaf(dz,z0,oz));
    float x1 = clip1(fmaf(dx,z1,ox)), y1 = clip1(fmaf(dy,z1,oy)), w1 = clip1(fmaf(dz,z1,oz));
    half8 bcf0 = (half8)(_Float16)0, bcf1 = (half8)(_Float16)0;
    if (q < 2){
      int o0i = (int)oidw[sidx0];
      int o1i = (int)oidw[sidx1];
      bcf0 = *(const half8*)&Geo[o0i*16 + q*8];    // k0..15: [od0(dead), geo0..14]
      bcf1 = *(const half8*)&Geo[o1i*16 + q*8];
    } else if (q == 2){
      unsigned int* u0p = (unsigned int*)&bcf0;    // k16..21 = pos/dir
      u0p[0] = pkh(x0,y0); u0p[1] = pkh(w0,dx); u0p[2] = pkh(dy,dz); u0p[3] = 0u;
      unsigned int* u1p = (unsigned int*)&bcf1;
      u1p[0] = pkh(x1,y1); u1p[1] = pkh(w1,dx); u1p[2] = pkh(dy,dz); u1p[3] = 0u;
    }
    #pragma unroll
    for(int t=0;t<4;t++){
      float4_ a0 = __builtin_amdgcn_mfma_f32_16x16x32_f16(aWc1T[t], bcf0, bc1v[t], 0,0,0);
      float4_ a1 = __builtin_amdgcn_mfma_f32_16x16x32_f16(aWc1T[t], bcf1, bc1v[t], 0,0,0);
      storeH(H0, a0, t, hbase);
      storeH(H1, a1, t, hbase);
    }
    LGKM0();
    half8 h00 = *(const half8*)&H0[lread];
    half8 h01 = *(const half8*)&H0[512 + lread];
    half8 h10 = *(const half8*)&H1[lread];
    half8 h11 = *(const half8*)&H1[512 + lread];
    float4_ oc0 = __builtin_amdgcn_mfma_f32_16x16x32_f16(aWc2T[0], h00, bTc, 0,0,0);
    oc0 = __builtin_amdgcn_mfma_f32_16x16x32_f16(aWc2T[1], h01, oc0, 0,0,0);
    float4_ oc1 = __builtin_amdgcn_mfma_f32_16x16x32_f16(aWc2T[0], h10, bTc, 0,0,0);
    oc1 = __builtin_amdgcn_mfma_f32_16x16x32_f16(aWc2T[1], h11, oc1, 0,0,0);
    if (q==0){
      float g0w = wLw[sidx0];
      if (g0w > 1e-4f){
        accR = fmaf(g0w, sigmoidf_(oc0[0]), accR);
        accG = fmaf(g0w, sigmoidf_(oc0[1]), accG);
        accB = fmaf(g0w, sigmoidf_(oc0[2]), accB);
      }
      accW += g0w;
      float g1w = wLw[sidx1];
      if (g1w > 1e-4f){
        accR = fmaf(g1w, sigmoidf_(oc1[0]), accR);
        accG = fmaf(g1w, sigmoidf_(oc1[1]), accG);
        accB = fmaf(g1w, sigmoidf_(oc1[2]), accB);
      }
      accW += g1w;
    }
    LGKM0();   // WAR guard: H bufs reused next pair
  }

  // ---------- wave reduce + output ----------
  #pragma unroll
  for(int off=32; off; off>>=1){
    accR += __shfl_down(accR, off, 64);
    accG += __shfl_down(accG, off, 64);
    accB += __shfl_down(accB, off, 64);
    accW += __shfl_down(accW, off, 64);
  }
  if (lane == 0){
    float bg = 1.f - accW;
    out[r*3+0] = accR + bg;
    out[r*3+1] = accG + bg;
    out[r*3+2] = accB + bg;
  }
}

extern "C" void kernel_launch(void* const* d_in, const int* in_sizes, int n_in,
                              void* d_out, int out_size, void* d_ws, size_t ws_size,
                              hipStream_t stream) {
  const float* ro  = (const float*)d_in[0];
  const float* rd  = (const float*)d_in[1];
  const float* W1  = (const float*)d_in[2];
  const float* b1  = (const float*)d_in[3];
  const float* W2  = (const float*)d_in[4];
  const float* b2  = (const float*)d_in[5];
  const float* Wc1 = (const float*)d_in[6];
  const float* bc1 = (const float*)d_in[7];
  const float* Wc2 = (const float*)d_in[8];
  const float* bc2 = (const float*)d_in[9];
  float* out = (float*)d_out;

  unsigned short* wb = (unsigned short*)d_ws;   // 6144 f16 fragment words

  prep_weights<<<dim3(24), dim3(256), 0, stream>>>(W1, W2, Wc1, Wc2, wb);
  nerf_fused<<<dim3(NRAYS/4), dim3(256), 0, stream>>>(
      ro, rd, b1, b2, bc1, bc2, wb, out);
}

// Round 12
// 220.350 us; speedup vs baseline: 1.6336x; 1.0442x over previous
//
#include <hip/hip_runtime.h>
#include <hip/hip_fp16.h>
#include <math.h>

#define NRAYS 16384
#define HID 64

typedef float    float4_ __attribute__((ext_vector_type(4)));
typedef _Float16 half8   __attribute__((ext_vector_type(8)));
typedef __fp16   fp16x2  __attribute__((ext_vector_type(2)));

#define LGKM0() __asm__ __volatile__("s_waitcnt lgkmcnt(0)" ::: "memory")

__device__ __forceinline__ float clip1(float v){ return fminf(fmaxf(v,-1.f),1.f); }
__device__ __forceinline__ float softplusf_(float x){
  return fmaxf(x,0.f) + __logf(1.f + __expf(-fabsf(x)));
}
__device__ __forceinline__ float sigmoidf_(float x){
  return __fdividef(1.f, 1.f + __expf(-x));
}

// 1-inst HW pack: 2 floats -> 2 f16 (RTZ). a -> low16, b -> high16.
__device__ __forceinline__ unsigned int pkh(float a, float b){
  union { fp16x2 h; unsigned int u; } cv;
  cv.h = __builtin_amdgcn_cvt_pkrtz(a, b);
  return cv.u;
}
__device__ __forceinline__ unsigned long long pk64(float4_ a){
  return (unsigned long long)pkh(a[0],a[1]) | ((unsigned long long)pkh(a[2],a[3])<<32);
}

__device__ __forceinline__ void load_ray(const float* ro, const float* rd, int r,
    float& ox,float& oy,float& oz,float& dx,float& dy,float& dz){
  ox=ro[3*r]; oy=ro[3*r+1]; oz=ro[3*r+2];
  dx=rd[3*r]; dy=rd[3*r+1]; dz=rd[3*r+2];
  float inv = 1.f/sqrtf(dx*dx+dy*dy+dz*dz);
  dx*=inv; dy*=inv; dz*=inv;
}

__device__ __forceinline__ void aabb_nf(float ox,float oy,float oz,float dx,float dy,float dz,
    float& nears,float& fars){
  float dsx = (fabsf(dx)<1e-8f)?1e-8f:dx;
  float dsy = (fabsf(dy)<1e-8f)?1e-8f:dy;
  float dsz = (fabsf(dz)<1e-8f)?1e-8f:dz;
  float t1x=(-1.f-ox)/dsx, t2x=(1.f-ox)/dsx;
  float t1y=(-1.f-oy)/dsy, t2y=(1.f-oy)/dsy;
  float t1z=(-1.f-oz)/dsz, t2z=(1.f-oz)/dsz;
  float nr = fmaxf(fmaxf(fminf(t1x,t2x),fminf(t1y,t2y)),fminf(t1z,t2z));
  float fr = fminf(fminf(fmaxf(t1x,t2x),fmaxf(t1y,t2y)),fmaxf(t1z,t2z));
  fars  = fmaxf(fminf(fr,5.f),0.2f);
  nears = fminf(fmaxf(nr,0.2f),5.f);
}

// wave-level exclusive scan over per-lane chunk sums; no barriers.
__device__ __forceinline__ float wave_excl_chunk(float chunk, int lane, float& total){
  float incl = chunk;
  #pragma unroll
  for(int off=1; off<64; off<<=1){
    float n = __shfl_up(incl, off, 64);
    if (lane >= off) incl += n;
  }
  total = __shfl(incl, 63, 64);
  return incl - chunk;
}

// ---------------- weight prep: f16 A-fragments (transposed weights) ----------------
// A-frag: lane l holds A[m=l&15][k=(l>>4)*8+j]. 12 slots of 64 lanes x 8 halves:
// slots 0..3 : W1^T  (M-tile mt: m=h=mt*16+c):  A = W1[k][h], k>=3 -> 0
// slots 4..5 : W2^T  (K-step ks: k=h=ks*32+..): A = W2[h][od=c]
// slots 6..9 : Wc1^T (M-tile mt), PERMUTED k:   k=0 -> 0 row (od0=sigma unused);
//              k in 1..15 -> geo_{k-1} (Wc1 row 5+k); k in 16..21 -> pos/dir
//              (Wc1 row k-16); k>=22 -> 0
// slots 10..11: Wc2^T: A = (c<3)? Wc2[h][c] : 0
__global__ void prep_weights(const float* __restrict__ W1, const float* __restrict__ W2,
                             const float* __restrict__ Wc1, const float* __restrict__ Wc2,
                             unsigned short* __restrict__ wb){
  int idx = blockIdx.x*256 + threadIdx.x;
  if (idx >= 6144) return;
  int f = idx>>3, j = idx&7, lane = f&63, slot = f>>6, q = lane>>4, c = lane&15;
  int k = q*8+j;
  float v = 0.f;
  if (slot < 4){        if (k<3) v = W1[k*HID + slot*16 + c]; }
  else if (slot < 6){   int h=(slot-4)*32+k; v = W2[h*16 + c]; }
  else if (slot < 10){  int mt=slot-6;
                        int row = (k==0)? -1 : (k<16 ? 5+k : (k<22 ? k-16 : -1));
                        if (row>=0) v = Wc1[row*HID + mt*16 + c]; }
  else {                int h=(slot-10)*32+k; if (c<3) v = Wc2[h*3 + c]; }
  wb[idx] = __half_as_ushort(__float2half_rn(v));
}

// relu + pack a layer-1 C-tile (4 h-rows, sample c) -> one b64 into frag-major H
__device__ __forceinline__ void storeH(unsigned short* H, float4_ a, int t, int hbase){
  unsigned long long dd =
      (unsigned long long)pkh(fmaxf(a[0],0.f), fmaxf(a[1],0.f))
    | ((unsigned long long)pkh(fmaxf(a[2],0.f), fmaxf(a[3],0.f))<<32);
  *(unsigned long long*)&H[hbase + t*256] = dd;
}

// ====== fully fused NeRF: 1 WAVE per ray, 2 rays/block (128 thr), no __syncthreads ======
// LDS/wave ~15 KB -> 30 KB/block -> 5 blocks/CU (2.5 waves/SIMD).
__global__ __launch_bounds__(128) void nerf_fused(
    const float* __restrict__ ro, const float* __restrict__ rd,
    const float* __restrict__ b1, const float* __restrict__ b2,
    const float* __restrict__ bc1, const float* __restrict__ bc2,
    const unsigned short* __restrict__ wb, float* __restrict__ out)
{
  __shared__ __align__(16) unsigned short Hfrag[2][2][1024];  // 8 KB
  __shared__ __align__(16) unsigned short GeoAll[2][4096];    // 16 KB: od0..15 per sample
  __shared__ __align__(16) unsigned short sig16[2][256];      // 1 KB: f16 sigma (coarse+fine)
  __shared__ __align__(16) float zBs[2][128];                 // 1 KB
  __shared__ __align__(16) float zMc[2][264];                 // ~2 KB: cdf (early) / zM+oid (late)
  __shared__ __align__(16) float wL[2][256];                  // 2 KB

  const int tid = threadIdx.x, lane = tid&63, wv = tid>>6;
  const int q = lane>>4, c = lane&15;
  const int r = blockIdx.x*2 + wv;

  float ox,oy,oz,dx,dy,dz;
  load_ray(ro,rd,r,ox,oy,oz,dx,dy,dz);
  float nears,fars; aabb_nf(ox,oy,oz,dx,dy,dz,nears,fars);
  const float step  = (fars-nears)*(1.f/127.f);
  const float sdist = (fars-nears)*(1.f/128.f);
  const bool asc = (nears <= fars);

  const half8* WF = (const half8*)wb;
  half8 aW1T[4], aW2T[2], aWc1T[4], aWc2T[2];
  #pragma unroll
  for(int t=0;t<4;t++){ aW1T[t] = WF[t*64+lane]; aWc1T[t] = WF[(6+t)*64+lane]; }
  #pragma unroll
  for(int k=0;k<2;k++){ aW2T[k] = WF[(4+k)*64+lane]; aWc2T[k] = WF[(10+k)*64+lane]; }
  float4_ b1v[4], bc1v[4];
  #pragma unroll
  for(int t=0;t<4;t++){
    b1v[t]  = *(const float4_*)&b1[t*16+q*4];
    bc1v[t] = *(const float4_*)&bc1[t*16+q*4];
  }
  const float4_ bTd = *(const float4_*)&b2[q*4];
  float4_ bTc = (float4_){0.f,0.f,0.f,0.f};
  if (q==0){ bTc[0]=bc2[0]; bTc[1]=bc2[1]; bTc[2]=bc2[2]; }

  unsigned short* H0 = &Hfrag[wv][0][0];
  unsigned short* H1 = &Hfrag[wv][1][0];
  unsigned short* Geo = &GeoAll[wv][0];
  unsigned short* sgw = sig16[wv];
  float* zBsw = zBs[wv];
  float* cdfw = zMc[wv];          // alias: cdf lives here until merge overwrites
  float* zMw  = zMc[wv];          // merged z (low 8 bits = origin id)
  float* wLw  = wL[wv];
  const int hbase = (q>>1)*128 + c*8 + (q&1)*4;   // ushort index (writer)
  const int lread = lane*8;                        // ushort index (reader)

  // ---------- pass 0: coarse density (4 pair-iterations) ----------
  #pragma unroll
  for(int p=0;p<4;p++){
    const int sidx0 = p*32 + c, sidx1 = p*32 + 16 + c;
    half8 bf0 = (half8)(_Float16)0, bf1 = (half8)(_Float16)0;
    if (q==0){
      float z0 = fmaf(step,(float)sidx0,nears);
      float z1 = fmaf(step,(float)sidx1,nears);
      unsigned int* u0p = (unsigned int*)&bf0;
      u0p[0] = pkh(clip1(fmaf(dx,z0,ox)), clip1(fmaf(dy,z0,oy)));
      u0p[1] = pkh(clip1(fmaf(dz,z0,oz)), 0.f);
      unsigned int* u1p = (unsigned int*)&bf1;
      u1p[0] = pkh(clip1(fmaf(dx,z1,ox)), clip1(fmaf(dy,z1,oy)));
      u1p[1] = pkh(clip1(fmaf(dz,z1,oz)), 0.f);
    }
    #pragma unroll
    for(int t=0;t<4;t++){
      float4_ a0 = __builtin_amdgcn_mfma_f32_16x16x32_f16(aW1T[t], bf0, b1v[t], 0,0,0);
      float4_ a1 = __builtin_amdgcn_mfma_f32_16x16x32_f16(aW1T[t], bf1, b1v[t], 0,0,0);
      storeH(H0, a0, t, hbase);
      storeH(H1, a1, t, hbase);
    }
    LGKM0();
    half8 h00 = *(const half8*)&H0[lread];
    half8 h01 = *(const half8*)&H0[512 + lread];
    half8 h10 = *(const half8*)&H1[lread];
    half8 h11 = *(const half8*)&H1[512 + lread];
    float4_ o0 = __builtin_amdgcn_mfma_f32_16x16x32_f16(aW2T[0], h00, bTd, 0,0,0);
    o0 = __builtin_amdgcn_mfma_f32_16x16x32_f16(aW2T[1], h01, o0, 0,0,0);
    float4_ o1 = __builtin_amdgcn_mfma_f32_16x16x32_f16(aW2T[0], h10, bTd, 0,0,0);
    o1 = __builtin_amdgcn_mfma_f32_16x16x32_f16(aW2T[1], h11, o1, 0,0,0);
    *(unsigned long long*)&Geo[sidx0*16 + q*4] = pk64(o0);
    *(unsigned long long*)&Geo[sidx1*16 + q*4] = pk64(o1);
    if (q==0){
      sgw[sidx0] = __half_as_ushort(__float2half_rn(softplusf_(o0[0])));
      sgw[sidx1] = __half_as_ushort(__float2half_rn(softplusf_(o1[0])));
    }
    LGKM0();   // WAR guard before H reuse
  }

  // ---------- pdf: wave-local exp-space scan + cdf (2 elems/lane) ----------
  {
    union { unsigned int u; __half2 h; } sp;
    sp.u = *(const unsigned int*)&sgw[2*lane];
    float s0 = __half2float(__low2half(sp.h));
    float s1 = __half2float(__high2half(sp.h));
    float d0 = (2*lane   < 127) ? step*s0 : 0.f;
    float d1 = (2*lane+1 < 127) ? step*s1 : 0.f;
    float tot;
    float e0 = wave_excl_chunk(d0+d1, lane, tot);
    float w0 = (1.f-__expf(-d0))*__expf(-e0);
    float w1 = (1.f-__expf(-d1))*__expf(-(e0+d0));
    float ww0 = (lane>=1 && 2*lane<127) ? w0+1e-5f : 0.f;   // i=0 excluded
    float ww1 = (2*lane+1 < 127) ? w1+1e-5f : 0.f;
    float wsum;
    float ce0 = wave_excl_chunk(ww0+ww1, lane, wsum);
    float inv = __fdividef(1.f, wsum);
    cdfw[2*lane]   = (ce0+ww0)*inv;
    cdfw[2*lane+1] = (ce0+ww0+ww1)*inv;                     // cdf[127] written, never read
  }
  LGKM0();

  // ---------- inverse-CDF sampling (2 fine samples/lane), stored z-sorted ----------
  {
    const float u0c = 0.5f/128.f;
    const float du = (1.f - 1.f/128.f)/127.f;
    #pragma unroll
    for(int j=0;j<2;j++){
      int k = lane + j*64;
      float u = fmaf(du,(float)k,u0c);
      int lo=0, hi=127;
      while(lo<hi){ int m=(lo+hi)>>1; if (cdfw[m] <= u) lo=m+1; else hi=m; }
      int below = max(lo-1,0), above = min(lo,126);
      float c0 = cdfw[below], c1 = cdfw[above];
      float bb0 = nears + step*((float)below + 0.5f);
      float bb1 = nears + step*((float)above + 0.5f);
      float den = c1 - c0; if (den < 1e-5f) den = 1.f;
      float zf = bb0 + (u - c0)/den*(bb1 - bb0);
      zBsw[asc ? k : 127-k] = zf;
    }
  }
  LGKM0();

  // ---------- pass 1: fine density, processed in z-sorted order ----------
  #pragma unroll
  for(int p=0;p<4;p++){
    const int sidx0 = p*32 + c, sidx1 = p*32 + 16 + c;
    half8 bf0 = (half8)(_Float16)0, bf1 = (half8)(_Float16)0;
    if (q==0){
      float z0 = zBsw[sidx0];
      float z1 = zBsw[sidx1];
      unsigned int* u0p = (unsigned int*)&bf0;
      u0p[0] = pkh(clip1(fmaf(dx,z0,ox)), clip1(fmaf(dy,z0,oy)));
      u0p[1] = pkh(clip1(fmaf(dz,z0,oz)), 0.f);
      unsigned int* u1p = (unsigned int*)&bf1;
      u1p[0] = pkh(clip1(fmaf(dx,z1,ox)), clip1(fmaf(dy,z1,oy)));
      u1p[1] = pkh(clip1(fmaf(dz,z1,oz)), 0.f);
    }
    #pragma unroll
    for(int t=0;t<4;t++){
      float4_ a0 = __builtin_amdgcn_mfma_f32_16x16x32_f16(aW1T[t], bf0, b1v[t], 0,0,0);
      float4_ a1 = __builtin_amdgcn_mfma_f32_16x16x32_f16(aW1T[t], bf1, b1v[t], 0,0,0);
      storeH(H0, a0, t, hbase);
      storeH(H1, a1, t, hbase);
    }
    LGKM0();
    half8 h00 = *(const half8*)&H0[lread];
    half8 h01 = *(const half8*)&H0[512 + lread];
    half8 h10 = *(const half8*)&H1[lread];
    half8 h11 = *(const half8*)&H1[512 + lread];
    float4_ o0 = __builtin_amdgcn_mfma_f32_16x16x32_f16(aW2T[0], h00, bTd, 0,0,0);
    o0 = __builtin_amdgcn_mfma_f32_16x16x32_f16(aW2T[1], h01, o0, 0,0,0);
    float4_ o1 = __builtin_amdgcn_mfma_f32_16x16x32_f16(aW2T[0], h10, bTd, 0,0,0);
    o1 = __builtin_amdgcn_mfma_f32_16x16x32_f16(aW2T[1], h11, o1, 0,0,0);
    *(unsigned long long*)&Geo[(128+sidx0)*16 + q*4] = pk64(o0);
    *(unsigned long long*)&Geo[(128+sidx1)*16 + q*4] = pk64(o1);
    if (q==0){
      sgw[128+sidx0] = __half_as_ushort(__float2half_rn(softplusf_(o0[0])));
      sgw[128+sidx1] = __half_as_ushort(__float2half_rn(softplusf_(o1[0])));
    }
    LGKM0();
  }

  // ---------- merge: rank by binary search; write z with oid packed in low 8 bits ----------
  #pragma unroll
  for(int j=0;j<2;j++){
    int sA = lane + j*64;
    int i = asc ? sA : 127-sA;
    float myz = fmaf(step,(float)i,nears);
    int lo=0, hi=128;
    while(lo<hi){ int m=(lo+hi)>>1; if (zBsw[m] < myz) lo=m+1; else hi=m; }
    int pos = sA + lo;
    zMw[pos] = __uint_as_float((__float_as_uint(myz) & ~255u) | (unsigned)i);
  }
  #pragma unroll
  for(int j=0;j<2;j++){
    int k = lane + j*64;
    float myz = zBsw[k];
    int lo=0, hi=128;                 // register-only search over computed coarse z
    while(lo<hi){
      int m=(lo+hi)>>1;
      float Am = fmaf(step,(float)(asc?m:127-m),nears);
      if (Am <= myz) lo=m+1; else hi=m;
    }
    int pos = k + lo;
    zMw[pos] = __uint_as_float((__float_as_uint(myz) & ~255u) | (unsigned)(128+k));
  }
  LGKM0();

  // ---------- composite: wave-local exp-space scan (4 elems/lane), sigma via oid ----------
  {
    float4_ z4 = *(const float4_*)&zMw[4*lane];
    float z5 = zMw[4*lane+4];                      // lane63 reads pad (unused via select)
    float sg0 = __half2float(*(const __half*)&sgw[__float_as_uint(z4[0]) & 255u]);
    float sg1 = __half2float(*(const __half*)&sgw[__float_as_uint(z4[1]) & 255u]);
    float sg2 = __half2float(*(const __half*)&sgw[__float_as_uint(z4[2]) & 255u]);
    float sg3 = __half2float(*(const __half*)&sgw[__float_as_uint(z4[3]) & 255u]);
    float d0 = (z4[1]-z4[0])*sg0;
    float d1 = (z4[2]-z4[1])*sg1;
    float d2 = (z4[3]-z4[2])*sg2;
    float dl = (lane==63) ? sdist : (z5 - z4[3]);
    float d3 = dl*sg3;
    float tot;
    float S = wave_excl_chunk(d0+d1+d2+d3, lane, tot);
    float4_ w4;
    w4[0] = (1.f-__expf(-d0))*__expf(-S); S += d0;
    w4[1] = (1.f-__expf(-d1))*__expf(-S); S += d1;
    w4[2] = (1.f-__expf(-d2))*__expf(-S); S += d2;
    w4[3] = (1.f-__expf(-d3))*__expf(-S);
    *(float4_*)&wLw[4*lane] = w4;
  }
  LGKM0();

  // ---------- render: color MLP only (geo gathered via packed oid), 8 pair-iterations ----------
  float accR=0.f, accG=0.f, accB=0.f, accW=0.f;
  #pragma unroll
  for(int p=0;p<8;p++){
    const int sidx0 = p*32 + c, sidx1 = p*32 + 16 + c;
    float z0 = zMw[sidx0], z1 = zMw[sidx1];
    int o0i = (int)(__float_as_uint(z0) & 255u);
    int o1i = (int)(__float_as_uint(z1) & 255u);
    float x0 = clip1(fmaf(dx,z0,ox)), y0 = clip1(fmaf(dy,z0,oy)), w0 = clip1(fmaf(dz,z0,oz));
    float x1 = clip1(fmaf(dx,z1,ox)), y1 = clip1(fmaf(dy,z1,oy)), w1 = clip1(fmaf(dz,z1,oz));
    half8 bcf0 = (half8)(_Float16)0, bcf1 = (half8)(_Float16)0;
    if (q < 2){
      bcf0 = *(const half8*)&Geo[o0i*16 + q*8];    // k0..15: [od0(dead), geo0..14]
      bcf1 = *(const half8*)&Geo[o1i*16 + q*8];
    } else if (q == 2){
      unsigned int* u0p = (unsigned int*)&bcf0;    // k16..21 = pos/dir
      u0p[0] = pkh(x0,y0); u0p[1] = pkh(w0,dx); u0p[2] = pkh(dy,dz); u0p[3] = 0u;
      unsigned int* u1p = (unsigned int*)&bcf1;
      u1p[0] = pkh(x1,y1); u1p[1] = pkh(w1,dx); u1p[2] = pkh(dy,dz); u1p[3] = 0u;
    }
    #pragma unroll
    for(int t=0;t<4;t++){
      float4_ a0 = __builtin_amdgcn_mfma_f32_16x16x32_f16(aWc1T[t], bcf0, bc1v[t], 0,0,0);
      float4_ a1 = __builtin_amdgcn_mfma_f32_16x16x32_f16(aWc1T[t], bcf1, bc1v[t], 0,0,0);
      storeH(H0, a0, t, hbase);
      storeH(H1, a1, t, hbase);
    }
    LGKM0();
    half8 h00 = *(const half8*)&H0[lread];
    half8 h01 = *(const half8*)&H0[512 + lread];
    half8 h10 = *(const half8*)&H1[lread];
    half8 h11 = *(const half8*)&H1[512 + lread];
    float4_ oc0 = __builtin_amdgcn_mfma_f32_16x16x32_f16(aWc2T[0], h00, bTc, 0,0,0);
    oc0 = __builtin_amdgcn_mfma_f32_16x16x32_f16(aWc2T[1], h01, oc0, 0,0,0);
    float4_ oc1 = __builtin_amdgcn_mfma_f32_16x16x32_f16(aWc2T[0], h10, bTc, 0,0,0);
    oc1 = __builtin_amdgcn_mfma_f32_16x16x32_f16(aWc2T[1], h11, oc1, 0,0,0);
    if (q==0){
      float g0w = wLw[sidx0];
      if (g0w > 1e-4f){
        accR = fmaf(g0w, sigmoidf_(oc0[0]), accR);
        accG = fmaf(g0w, sigmoidf_(oc0[1]), accG);
        accB = fmaf(g0w, sigmoidf_(oc0[2]), accB);
      }
      accW += g0w;
      float g1w = wLw[sidx1];
      if (g1w > 1e-4f){
        accR = fmaf(g1w, sigmoidf_(oc1[0]), accR);
        accG = fmaf(g1w, sigmoidf_(oc1[1]), accG);
        accB = fmaf(g1w, sigmoidf_(oc1[2]), accB);
      }
      accW += g1w;
    }
    LGKM0();   // WAR guard: H bufs reused next pair
  }

  // ---------- wave reduce + output ----------
  #pragma unroll
  for(int off=32; off; off>>=1){
    accR += __shfl_down(accR, off, 64);
    accG += __shfl_down(accG, off, 64);
    accB += __shfl_down(accB, off, 64);
    accW += __shfl_down(accW, off, 64);
  }
  if (lane == 0){
    float bg = 1.f - accW;
    out[r*3+0] = accR + bg;
    out[r*3+1] = accG + bg;
    out[r*3+2] = accB + bg;
  }
}

extern "C" void kernel_launch(void* const* d_in, const int* in_sizes, int n_in,
                              void* d_out, int out_size, void* d_ws, size_t ws_size,
                              hipStream_t stream) {
  const float* ro  = (const float*)d_in[0];
  const float* rd  = (const float*)d_in[1];
  const float* W1  = (const float*)d_in[2];
  const float* b1  = (const float*)d_in[3];
  const float* W2  = (const float*)d_in[4];
  const float* b2  = (const float*)d_in[5];
  const float* Wc1 = (const float*)d_in[6];
  const float* bc1 = (const float*)d_in[7];
  const float* Wc2 = (const float*)d_in[8];
  const float* bc2 = (const float*)d_in[9];
  float* out = (float*)d_out;

  unsigned short* wb = (unsigned short*)d_ws;   // 6144 f16 fragment words

  prep_weights<<<dim3(24), dim3(256), 0, stream>>>(W1, W2, Wc1, Wc2, wb);
  nerf_fused<<<dim3(NRAYS/2), dim3(128), 0, stream>>>(
      ro, rd, b1, b2, bc1, bc2, wb, out);
}

// Round 13
// 207.361 us; speedup vs baseline: 1.7359x; 1.0626x over previous
//
#include <hip/hip_runtime.h>
#include <hip/hip_fp16.h>
#include <math.h>

#define NRAYS 16384
#define HID 64

typedef float    float4_ __attribute__((ext_vector_type(4)));
typedef _Float16 half8   __attribute__((ext_vector_type(8)));
typedef __fp16   fp16x2  __attribute__((ext_vector_type(2)));

#define LGKM0() __asm__ __volatile__("s_waitcnt lgkmcnt(0)" ::: "memory")

__device__ __forceinline__ float clip1(float v){ return fminf(fmaxf(v,-1.f),1.f); }
__device__ __forceinline__ float softplusf_(float x){
  return fmaxf(x,0.f) + __logf(1.f + __expf(-fabsf(x)));
}
__device__ __forceinline__ float sigmoidf_(float x){
  return __fdividef(1.f, 1.f + __expf(-x));
}

// 1-inst HW pack: 2 floats -> 2 f16 (RTZ). a -> low16, b -> high16.
__device__ __forceinline__ unsigned int pkh(float a, float b){
  union { fp16x2 h; unsigned int u; } cv;
  cv.h = __builtin_amdgcn_cvt_pkrtz(a, b);
  return cv.u;
}
__device__ __forceinline__ unsigned long long pk64(float4_ a){
  return (unsigned long long)pkh(a[0],a[1]) | ((unsigned long long)pkh(a[2],a[3])<<32);
}
// packed relu on 2 f16 lanes in one VOP3P inst
__device__ __forceinline__ unsigned int relu_pk(unsigned int x){
  unsigned int y;
  __asm__("v_pk_max_f16 %0, %1, 0" : "=v"(y) : "v"(x));
  return y;
}

__device__ __forceinline__ void load_ray(const float* ro, const float* rd, int r,
    float& ox,float& oy,float& oz,float& dx,float& dy,float& dz){
  ox=ro[3*r]; oy=ro[3*r+1]; oz=ro[3*r+2];
  dx=rd[3*r]; dy=rd[3*r+1]; dz=rd[3*r+2];
  float inv = 1.f/sqrtf(dx*dx+dy*dy+dz*dz);
  dx*=inv; dy*=inv; dz*=inv;
}

__device__ __forceinline__ void aabb_nf(float ox,float oy,float oz,float dx,float dy,float dz,
    float& nears,float& fars){
  float dsx = (fabsf(dx)<1e-8f)?1e-8f:dx;
  float dsy = (fabsf(dy)<1e-8f)?1e-8f:dy;
  float dsz = (fabsf(dz)<1e-8f)?1e-8f:dz;
  float t1x=(-1.f-ox)/dsx, t2x=(1.f-ox)/dsx;
  float t1y=(-1.f-oy)/dsy, t2y=(1.f-oy)/dsy;
  float t1z=(-1.f-oz)/dsz, t2z=(1.f-oz)/dsz;
  float nr = fmaxf(fmaxf(fminf(t1x,t2x),fminf(t1y,t2y)),fminf(t1z,t2z));
  float fr = fminf(fminf(fmaxf(t1x,t2x),fmaxf(t1y,t2y)),fmaxf(t1z,t2z));
  fars  = fmaxf(fminf(fr,5.f),0.2f);
  nears = fminf(fmaxf(nr,0.2f),5.f);
}

// wave-level exclusive scan over per-lane chunk sums; no barriers.
__device__ __forceinline__ float wave_excl_chunk(float chunk, int lane, float& total){
  float incl = chunk;
  #pragma unroll
  for(int off=1; off<64; off<<=1){
    float n = __shfl_up(incl, off, 64);
    if (lane >= off) incl += n;
  }
  total = __shfl(incl, 63, 64);
  return incl - chunk;
}

// ---------------- weight prep: f16 A-fragments (transposed weights) ----------------
// A-frag: lane l holds A[m=l&15][k=(l>>4)*8+j]. 12 slots of 64 lanes x 8 halves:
// slots 0..3 : W1^T  (M-tile mt: m=h=mt*16+c):  A = W1[k][h], k>=3 -> 0
// slots 4..5 : W2^T  (K-step ks: k=h=ks*32+..): A = W2[h][od=c]
// slots 6..9 : Wc1^T (M-tile mt), PERMUTED k:   k=0 -> 0 row (od0=sigma unused);
//              k in 1..15 -> geo_{k-1} (Wc1 row 5+k); k in 16..21 -> pos/dir
//              (Wc1 row k-16); k>=22 -> 0
// slots 10..11: Wc2^T: A = (c<3)? Wc2[h][c] : 0
__global__ void prep_weights(const float* __restrict__ W1, const float* __restrict__ W2,
                             const float* __restrict__ Wc1, const float* __restrict__ Wc2,
                             unsigned short* __restrict__ wb){
  int idx = blockIdx.x*256 + threadIdx.x;
  if (idx >= 6144) return;
  int f = idx>>3, j = idx&7, lane = f&63, slot = f>>6, q = lane>>4, c = lane&15;
  int k = q*8+j;
  float v = 0.f;
  if (slot < 4){        if (k<3) v = W1[k*HID + slot*16 + c]; }
  else if (slot < 6){   int h=(slot-4)*32+k; v = W2[h*16 + c]; }
  else if (slot < 10){  int mt=slot-6;
                        int row = (k==0)? -1 : (k<16 ? 5+k : (k<22 ? k-16 : -1));
                        if (row>=0) v = Wc1[row*HID + mt*16 + c]; }
  else {                int h=(slot-10)*32+k; if (c<3) v = Wc2[h*3 + c]; }
  wb[idx] = __half_as_ushort(__float2half_rn(v));
}

// pack a layer-1 C-tile (4 h-rows, sample c) + packed relu -> one b64 into frag-major H
__device__ __forceinline__ void storeH(unsigned short* H, float4_ a, int t, int hbase){
  unsigned int lo = relu_pk(pkh(a[0],a[1]));
  unsigned int hi = relu_pk(pkh(a[2],a[3]));
  *(unsigned long long*)&H[hbase + t*256] =
      (unsigned long long)lo | ((unsigned long long)hi<<32);
}

// ====== fully fused NeRF: 1 WAVE per ray, 2 rays/block (128 thr), no __syncthreads ======
__global__ __launch_bounds__(128) void nerf_fused(
    const float* __restrict__ ro, const float* __restrict__ rd,
    const float* __restrict__ b1, const float* __restrict__ b2,
    const float* __restrict__ bc1, const float* __restrict__ bc2,
    const unsigned short* __restrict__ wb, float* __restrict__ out)
{
  __shared__ __align__(16) unsigned short Hfrag[2][2][1024];  // 8 KB
  __shared__ __align__(16) unsigned short GeoAll[2][4096];    // 16 KB: od0..15 per sample
  __shared__ __align__(16) unsigned short sig16[2][256];      // 1 KB: f16 sigma (coarse+fine)
  __shared__ __align__(16) float zBs[2][128];                 // 1 KB
  __shared__ __align__(16) float zMc[2][264];                 // ~2 KB: cdf (early) / zM+oid (late)
  __shared__ __align__(16) float wL[2][256];                  // 2 KB

  const int tid = threadIdx.x, lane = tid&63, wv = tid>>6;
  const int q = lane>>4, c = lane&15;
  const int r = blockIdx.x*2 + wv;

  float ox,oy,oz,dx,dy,dz;
  load_ray(ro,rd,r,ox,oy,oz,dx,dy,dz);
  float nears,fars; aabb_nf(ox,oy,oz,dx,dy,dz,nears,fars);
  const float step  = (fars-nears)*(1.f/127.f);
  const float sdist = (fars-nears)*(1.f/128.f);
  const bool asc = (nears <= fars);

  const half8* WF = (const half8*)wb;
  half8 aW1T[4], aW2T[2], aWc1T[4], aWc2T[2];
  #pragma unroll
  for(int t=0;t<4;t++){ aW1T[t] = WF[t*64+lane]; aWc1T[t] = WF[(6+t)*64+lane]; }
  #pragma unroll
  for(int k=0;k<2;k++){ aW2T[k] = WF[(4+k)*64+lane]; aWc2T[k] = WF[(10+k)*64+lane]; }
  float4_ b1v[4], bc1v[4];
  #pragma unroll
  for(int t=0;t<4;t++){
    b1v[t]  = *(const float4_*)&b1[t*16+q*4];
    bc1v[t] = *(const float4_*)&bc1[t*16+q*4];
  }
  const float4_ bTd = *(const float4_*)&b2[q*4];
  float4_ bTc = (float4_){0.f,0.f,0.f,0.f};
  if (q==0){ bTc[0]=bc2[0]; bTc[1]=bc2[1]; bTc[2]=bc2[2]; }

  unsigned short* H0 = &Hfrag[wv][0][0];
  unsigned short* H1 = &Hfrag[wv][1][0];
  unsigned short* Geo = &GeoAll[wv][0];
  unsigned short* sgw = sig16[wv];
  float* zBsw = zBs[wv];
  float* cdfw = zMc[wv];          // alias: cdf lives here until merge overwrites
  float* zMw  = zMc[wv];          // merged z (low 8 bits = origin id)
  float* wLw  = wL[wv];
  const int hbase = (q>>1)*128 + c*8 + (q&1)*4;   // ushort index (writer)
  const int lread = lane*8;                        // ushort index (reader)

  // ---------- pass 0: coarse density (4 pair-iterations) ----------
  #pragma unroll
  for(int p=0;p<4;p++){
    const int sidx0 = p*32 + c, sidx1 = p*32 + 16 + c;
    half8 bf0 = (half8)(_Float16)0, bf1 = (half8)(_Float16)0;
    if (q==0){
      float z0 = fmaf(step,(float)sidx0,nears);
      float z1 = fmaf(step,(float)sidx1,nears);
      unsigned int* u0p = (unsigned int*)&bf0;
      u0p[0] = pkh(clip1(fmaf(dx,z0,ox)), clip1(fmaf(dy,z0,oy)));
      u0p[1] = pkh(clip1(fmaf(dz,z0,oz)), 0.f);
      unsigned int* u1p = (unsigned int*)&bf1;
      u1p[0] = pkh(clip1(fmaf(dx,z1,ox)), clip1(fmaf(dy,z1,oy)));
      u1p[1] = pkh(clip1(fmaf(dz,z1,oz)), 0.f);
    }
    #pragma unroll
    for(int t=0;t<4;t++){
      float4_ a0 = __builtin_amdgcn_mfma_f32_16x16x32_f16(aW1T[t], bf0, b1v[t], 0,0,0);
      float4_ a1 = __builtin_amdgcn_mfma_f32_16x16x32_f16(aW1T[t], bf1, b1v[t], 0,0,0);
      storeH(H0, a0, t, hbase);
      storeH(H1, a1, t, hbase);
    }
    LGKM0();
    half8 h00 = *(const half8*)&H0[lread];
    half8 h01 = *(const half8*)&H0[512 + lread];
    half8 h10 = *(const half8*)&H1[lread];
    half8 h11 = *(const half8*)&H1[512 + lread];
    float4_ o0 = __builtin_amdgcn_mfma_f32_16x16x32_f16(aW2T[0], h00, bTd, 0,0,0);
    o0 = __builtin_amdgcn_mfma_f32_16x16x32_f16(aW2T[1], h01, o0, 0,0,0);
    float4_ o1 = __builtin_amdgcn_mfma_f32_16x16x32_f16(aW2T[0], h10, bTd, 0,0,0);
    o1 = __builtin_amdgcn_mfma_f32_16x16x32_f16(aW2T[1], h11, o1, 0,0,0);
    *(unsigned long long*)&Geo[sidx0*16 + q*4] = pk64(o0);
    *(unsigned long long*)&Geo[sidx1*16 + q*4] = pk64(o1);
    if (q==0){
      sgw[sidx0] = __half_as_ushort(__float2half_rn(softplusf_(o0[0])));
      sgw[sidx1] = __half_as_ushort(__float2half_rn(softplusf_(o1[0])));
    }
    LGKM0();   // WAR guard before H reuse
  }

  // ---------- pdf: wave-local exp-space scan + cdf (2 elems/lane) ----------
  {
    union { unsigned int u; __half2 h; } sp;
    sp.u = *(const unsigned int*)&sgw[2*lane];
    float s0 = __half2float(__low2half(sp.h));
    float s1 = __half2float(__high2half(sp.h));
    float d0 = (2*lane   < 127) ? step*s0 : 0.f;
    float d1 = (2*lane+1 < 127) ? step*s1 : 0.f;
    float tot;
    float e0 = wave_excl_chunk(d0+d1, lane, tot);
    float w0 = (1.f-__expf(-d0))*__expf(-e0);
    float w1 = (1.f-__expf(-d1))*__expf(-(e0+d0));
    float ww0 = (lane>=1 && 2*lane<127) ? w0+1e-5f : 0.f;   // i=0 excluded
    float ww1 = (2*lane+1 < 127) ? w1+1e-5f : 0.f;
    float wsum;
    float ce0 = wave_excl_chunk(ww0+ww1, lane, wsum);
    float inv = __fdividef(1.f, wsum);
    cdfw[2*lane]   = (ce0+ww0)*inv;
    cdfw[2*lane+1] = (ce0+ww0+ww1)*inv;                     // cdf[127] written, never read
  }
  LGKM0();

  // ---------- inverse-CDF sampling (2 fine samples/lane), stored z-sorted ----------
  {
    const float u0c = 0.5f/128.f;
    const float du = (1.f - 1.f/128.f)/127.f;
    #pragma unroll
    for(int j=0;j<2;j++){
      int k = lane + j*64;
      float u = fmaf(du,(float)k,u0c);
      int lo=0, hi=127;
      while(lo<hi){ int m=(lo+hi)>>1; if (cdfw[m] <= u) lo=m+1; else hi=m; }
      int below = max(lo-1,0), above = min(lo,126);
      float c0 = cdfw[below], c1 = cdfw[above];
      float bb0 = nears + step*((float)below + 0.5f);
      float bb1 = nears + step*((float)above + 0.5f);
      float den = c1 - c0; if (den < 1e-5f) den = 1.f;
      float zf = bb0 + (u - c0)/den*(bb1 - bb0);
      zBsw[asc ? k : 127-k] = zf;
    }
  }
  LGKM0();

  // ---------- pass 1: fine density, processed in z-sorted order ----------
  #pragma unroll
  for(int p=0;p<4;p++){
    const int sidx0 = p*32 + c, sidx1 = p*32 + 16 + c;
    half8 bf0 = (half8)(_Float16)0, bf1 = (half8)(_Float16)0;
    if (q==0){
      float z0 = zBsw[sidx0];
      float z1 = zBsw[sidx1];
      unsigned int* u0p = (unsigned int*)&bf0;
      u0p[0] = pkh(clip1(fmaf(dx,z0,ox)), clip1(fmaf(dy,z0,oy)));
      u0p[1] = pkh(clip1(fmaf(dz,z0,oz)), 0.f);
      unsigned int* u1p = (unsigned int*)&bf1;
      u1p[0] = pkh(clip1(fmaf(dx,z1,ox)), clip1(fmaf(dy,z1,oy)));
      u1p[1] = pkh(clip1(fmaf(dz,z1,oz)), 0.f);
    }
    #pragma unroll
    for(int t=0;t<4;t++){
      float4_ a0 = __builtin_amdgcn_mfma_f32_16x16x32_f16(aW1T[t], bf0, b1v[t], 0,0,0);
      float4_ a1 = __builtin_amdgcn_mfma_f32_16x16x32_f16(aW1T[t], bf1, b1v[t], 0,0,0);
      storeH(H0, a0, t, hbase);
      storeH(H1, a1, t, hbase);
    }
    LGKM0();
    half8 h00 = *(const half8*)&H0[lread];
    half8 h01 = *(const half8*)&H0[512 + lread];
    half8 h10 = *(const half8*)&H1[lread];
    half8 h11 = *(const half8*)&H1[512 + lread];
    float4_ o0 = __builtin_amdgcn_mfma_f32_16x16x32_f16(aW2T[0], h00, bTd, 0,0,0);
    o0 = __builtin_amdgcn_mfma_f32_16x16x32_f16(aW2T[1], h01, o0, 0,0,0);
    float4_ o1 = __builtin_amdgcn_mfma_f32_16x16x32_f16(aW2T[0], h10, bTd, 0,0,0);
    o1 = __builtin_amdgcn_mfma_f32_16x16x32_f16(aW2T[1], h11, o1, 0,0,0);
    *(unsigned long long*)&Geo[(128+sidx0)*16 + q*4] = pk64(o0);
    *(unsigned long long*)&Geo[(128+sidx1)*16 + q*4] = pk64(o1);
    if (q==0){
      sgw[128+sidx0] = __half_as_ushort(__float2half_rn(softplusf_(o0[0])));
      sgw[128+sidx1] = __half_as_ushort(__float2half_rn(softplusf_(o1[0])));
    }
    LGKM0();
  }

  // ---------- merge: rank by binary search; write z with oid packed in low 8 bits ----------
  #pragma unroll
  for(int j=0;j<2;j++){
    int sA = lane + j*64;
    int i = asc ? sA : 127-sA;
    float myz = fmaf(step,(float)i,nears);
    int lo=0, hi=128;
    while(lo<hi){ int m=(lo+hi)>>1; if (zBsw[m] < myz) lo=m+1; else hi=m; }
    int pos = sA + lo;
    zMw[pos] = __uint_as_float((__float_as_uint(myz) & ~255u) | (unsigned)i);
  }
  #pragma unroll
  for(int j=0;j<2;j++){
    int k = lane + j*64;
    float myz = zBsw[k];
    int lo=0, hi=128;                 // register-only search over computed coarse z
    while(lo<hi){
      int m=(lo+hi)>>1;
      float Am = fmaf(step,(float)(asc?m:127-m),nears);
      if (Am <= myz) lo=m+1; else hi=m;
    }
    int pos = k + lo;
    zMw[pos] = __uint_as_float((__float_as_uint(myz) & ~255u) | (unsigned)(128+k));
  }
  LGKM0();

  // ---------- composite: wave-local exp-space scan (4 elems/lane), sigma via oid ----------
  {
    float4_ z4 = *(const float4_*)&zMw[4*lane];
    float z5 = zMw[4*lane+4];                      // lane63 reads pad (unused via select)
    float sg0 = __half2float(*(const __half*)&sgw[__float_as_uint(z4[0]) & 255u]);
    float sg1 = __half2float(*(const __half*)&sgw[__float_as_uint(z4[1]) & 255u]);
    float sg2 = __half2float(*(const __half*)&sgw[__float_as_uint(z4[2]) & 255u]);
    float sg3 = __half2float(*(const __half*)&sgw[__float_as_uint(z4[3]) & 255u]);
    float d0 = (z4[1]-z4[0])*sg0;
    float d1 = (z4[2]-z4[1])*sg1;
    float d2 = (z4[3]-z4[2])*sg2;
    float dl = (lane==63) ? sdist : (z5 - z4[3]);
    float d3 = dl*sg3;
    float tot;
    float S = wave_excl_chunk(d0+d1+d2+d3, lane, tot);
    float4_ w4;
    w4[0] = (1.f-__expf(-d0))*__expf(-S); S += d0;
    w4[1] = (1.f-__expf(-d1))*__expf(-S); S += d1;
    w4[2] = (1.f-__expf(-d2))*__expf(-S); S += d2;
    w4[3] = (1.f-__expf(-d3))*__expf(-S);
    *(float4_*)&wLw[4*lane] = w4;
  }
  LGKM0();

  // ---------- render: color MLP only (geo gathered via packed oid), 8 pair-iterations ----------
  float accR=0.f, accG=0.f, accB=0.f, accW=0.f;
  #pragma unroll
  for(int p=0;p<8;p++){
    const int sidx0 = p*32 + c, sidx1 = p*32 + 16 + c;
    float z0 = zMw[sidx0], z1 = zMw[sidx1];
    int o0i = (int)(__float_as_uint(z0) & 255u);
    int o1i = (int)(__float_as_uint(z1) & 255u);
    float x0 = clip1(fmaf(dx,z0,ox)), y0 = clip1(fmaf(dy,z0,oy)), w0 = clip1(fmaf(dz,z0,oz));
    float x1 = clip1(fmaf(dx,z1,ox)), y1 = clip1(fmaf(dy,z1,oy)), w1 = clip1(fmaf(dz,z1,oz));
    half8 bcf0 = (half8)(_Float16)0, bcf1 = (half8)(_Float16)0;
    if (q < 2){
      bcf0 = *(const half8*)&Geo[o0i*16 + q*8];    // k0..15: [od0(dead), geo0..14]
      bcf1 = *(const half8*)&Geo[o1i*16 + q*8];
    } else if (q == 2){
      unsigned int* u0p = (unsigned int*)&bcf0;    // k16..21 = pos/dir
      u0p[0] = pkh(x0,y0); u0p[1] = pkh(w0,dx); u0p[2] = pkh(dy,dz); u0p[3] = 0u;
      unsigned int* u1p = (unsigned int*)&bcf1;
      u1p[0] = pkh(x1,y1); u1p[1] = pkh(w1,dx); u1p[2] = pkh(dy,dz); u1p[3] = 0u;
    }
    #pragma unroll
    for(int t=0;t<4;t++){
      float4_ a0 = __builtin_amdgcn_mfma_f32_16x16x32_f16(aWc1T[t], bcf0, bc1v[t], 0,0,0);
      float4_ a1 = __builtin_amdgcn_mfma_f32_16x16x32_f16(aWc1T[t], bcf1, bc1v[t], 0,0,0);
      storeH(H0, a0, t, hbase);
      storeH(H1, a1, t, hbase);
    }
    LGKM0();
    half8 h00 = *(const half8*)&H0[lread];
    half8 h01 = *(const half8*)&H0[512 + lread];
    half8 h10 = *(const half8*)&H1[lread];
    half8 h11 = *(const half8*)&H1[512 + lread];
    float4_ oc0 = __builtin_amdgcn_mfma_f32_16x16x32_f16(aWc2T[0], h00, bTc, 0,0,0);
    oc0 = __builtin_amdgcn_mfma_f32_16x16x32_f16(aWc2T[1], h01, oc0, 0,0,0);
    float4_ oc1 = __builtin_amdgcn_mfma_f32_16x16x32_f16(aWc2T[0], h10, bTc, 0,0,0);
    oc1 = __builtin_amdgcn_mfma_f32_16x16x32_f16(aWc2T[1], h11, oc1, 0,0,0);
    if (q==0){
      float g0w = wLw[sidx0];
      if (g0w > 1e-4f){
        accR = fmaf(g0w, sigmoidf_(oc0[0]), accR);
        accG = fmaf(g0w, sigmoidf_(oc0[1]), accG);
        accB = fmaf(g0w, sigmoidf_(oc0[2]), accB);
      }
      accW += g0w;
      float g1w = wLw[sidx1];
      if (g1w > 1e-4f){
        accR = fmaf(g1w, sigmoidf_(oc1[0]), accR);
        accG = fmaf(g1w, sigmoidf_(oc1[1]), accG);
        accB = fmaf(g1w, sigmoidf_(oc1[2]), accB);
      }
      accW += g1w;
    }
    LGKM0();   // WAR guard: H bufs reused next pair
  }

  // ---------- wave reduce + output ----------
  #pragma unroll
  for(int off=32; off; off>>=1){
    accR += __shfl_down(accR, off, 64);
    accG += __shfl_down(accG, off, 64);
    accB += __shfl_down(accB, off, 64);
    accW += __shfl_down(accW, off, 64);
  }
  if (lane == 0){
    float bg = 1.f - accW;
    out[r*3+0] = accR + bg;
    out[r*3+1] = accG + bg;
    out[r*3+2] = accB + bg;
  }
}

extern "C" void kernel_launch(void* const* d_in, const int* in_sizes, int n_in,
                              void* d_out, int out_size, void* d_ws, size_t ws_size,
                              hipStream_t stream) {
  const float* ro  = (const float*)d_in[0];
  const float* rd  = (const float*)d_in[1];
  const float* W1  = (const float*)d_in[2];
  const float* b1  = (const float*)d_in[3];
  const float* W2  = (const float*)d_in[4];
  const float* b2  = (const float*)d_in[5];
  const float* Wc1 = (const float*)d_in[6];
  const float* bc1 = (const float*)d_in[7];
  const float* Wc2 = (const float*)d_in[8];
  const float* bc2 = (const float*)d_in[9];
  float* out = (float*)d_out;

  unsigned short* wb = (unsigned short*)d_ws;   // 6144 f16 fragment words

  prep_weights<<<dim3(24), dim3(256), 0, stream>>>(W1, W2, Wc1, Wc2, wb);
  nerf_fused<<<dim3(NRAYS/2), dim3(128), 0, stream>>>(
      ro, rd, b1, b2, bc1, bc2, wb, out);
}

// Round 14
// 203.885 us; speedup vs baseline: 1.7655x; 1.0171x over previous
//
#include <hip/hip_runtime.h>
#include <hip/hip_fp16.h>
#include <math.h>

#define NRAYS 16384
#define HID 64

typedef float    float4_ __attribute__((ext_vector_type(4)));
typedef _Float16 half8   __attribute__((ext_vector_type(8)));
typedef __fp16   fp16x2  __attribute__((ext_vector_type(2)));

__device__ __forceinline__ float clip1(float v){ return fminf(fmaxf(v,-1.f),1.f); }
__device__ __forceinline__ float softplusf_(float x){
  return fmaxf(x,0.f) + __logf(1.f + __expf(-fabsf(x)));
}
__device__ __forceinline__ float sigmoidf_(float x){
  return __fdividef(1.f, 1.f + __expf(-x));
}

// 1-inst HW pack: 2 floats -> 2 f16 (RTZ). a -> low16, b -> high16.
__device__ __forceinline__ unsigned int pkh(float a, float b){
  union { fp16x2 h; unsigned int u; } cv;
  cv.h = __builtin_amdgcn_cvt_pkrtz(a, b);
  return cv.u;
}
__device__ __forceinline__ unsigned long long pk64(float4_ a){
  return (unsigned long long)pkh(a[0],a[1]) | ((unsigned long long)pkh(a[2],a[3])<<32);
}
// packed relu on 2 f16 lanes in one VOP3P inst
__device__ __forceinline__ unsigned int relu_pk(unsigned int x){
  unsigned int y;
  __asm__("v_pk_max_f16 %0, %1, 0" : "=v"(y) : "v"(x));
  return y;
}

__device__ __forceinline__ void load_ray(const float* ro, const float* rd, int r,
    float& ox,float& oy,float& oz,float& dx,float& dy,float& dz){
  ox=ro[3*r]; oy=ro[3*r+1]; oz=ro[3*r+2];
  dx=rd[3*r]; dy=rd[3*r+1]; dz=rd[3*r+2];
  float inv = 1.f/sqrtf(dx*dx+dy*dy+dz*dz);
  dx*=inv; dy*=inv; dz*=inv;
}

__device__ __forceinline__ void aabb_nf(float ox,float oy,float oz,float dx,float dy,float dz,
    float& nears,float& fars){
  float dsx = (fabsf(dx)<1e-8f)?1e-8f:dx;
  float dsy = (fabsf(dy)<1e-8f)?1e-8f:dy;
  float dsz = (fabsf(dz)<1e-8f)?1e-8f:dz;
  float t1x=(-1.f-ox)/dsx, t2x=(1.f-ox)/dsx;
  float t1y=(-1.f-oy)/dsy, t2y=(1.f-oy)/dsy;
  float t1z=(-1.f-oz)/dsz, t2z=(1.f-oz)/dsz;
  float nr = fmaxf(fmaxf(fminf(t1x,t2x),fminf(t1y,t2y)),fminf(t1z,t2z));
  float fr = fminf(fminf(fmaxf(t1x,t2x),fmaxf(t1y,t2y)),fmaxf(t1z,t2z));
  fars  = fmaxf(fminf(fr,5.f),0.2f);
  nears = fminf(fmaxf(nr,0.2f),5.f);
}

// wave-level exclusive scan over per-lane chunk sums; no barriers.
__device__ __forceinline__ float wave_excl_chunk(float chunk, int lane, float& total){
  float incl = chunk;
  #pragma unroll
  for(int off=1; off<64; off<<=1){
    float n = __shfl_up(incl, off, 64);
    if (lane >= off) incl += n;
  }
  total = __shfl(incl, 63, 64);
  return incl - chunk;
}

// ---------------- weight prep: f16 A-fragments (transposed weights) ----------------
// A-frag: lane l holds A[m=l&15][k=(l>>4)*8+j]. 12 slots of 64 lanes x 8 halves:
// slots 0..3 : W1^T  (M-tile mt: m=h=mt*16+c):  A = W1[k][h], k>=3 -> 0
// slots 4..5 : W2^T  (K-step ks: k=h=ks*32+..): A = W2[h][od=c]
// slots 6..9 : Wc1^T (M-tile mt), PERMUTED k:   k=0 -> 0 row (od0=sigma unused);
//              k in 1..15 -> geo_{k-1} (Wc1 row 5+k); k in 16..21 -> pos/dir
//              (Wc1 row k-16); k>=22 -> 0
// slots 10..11: Wc2^T: A = (c<3)? Wc2[h][c] : 0
__global__ void prep_weights(const float* __restrict__ W1, const float* __restrict__ W2,
                             const float* __restrict__ Wc1, const float* __restrict__ Wc2,
                             unsigned short* __restrict__ wb){
  int idx = blockIdx.x*256 + threadIdx.x;
  if (idx >= 6144) return;
  int f = idx>>3, j = idx&7, lane = f&63, slot = f>>6, q = lane>>4, c = lane&15;
  int k = q*8+j;
  float v = 0.f;
  if (slot < 4){        if (k<3) v = W1[k*HID + slot*16 + c]; }
  else if (slot < 6){   int h=(slot-4)*32+k; v = W2[h*16 + c]; }
  else if (slot < 10){  int mt=slot-6;
                        int row = (k==0)? -1 : (k<16 ? 5+k : (k<22 ? k-16 : -1));
                        if (row>=0) v = Wc1[row*HID + mt*16 + c]; }
  else {                int h=(slot-10)*32+k; if (c<3) v = Wc2[h*3 + c]; }
  wb[idx] = __half_as_ushort(__float2half_rn(v));
}

// pack a layer-1 C-tile (4 h-rows, sample c) + packed relu -> one b64 into frag-major H
__device__ __forceinline__ void storeH(unsigned short* H, float4_ a, int t, int hbase){
  unsigned int lo = relu_pk(pkh(a[0],a[1]));
  unsigned int hi = relu_pk(pkh(a[2],a[3]));
  *(unsigned long long*)&H[hbase + t*256] =
      (unsigned long long)lo | ((unsigned long long)hi<<32);
}

// ====== fully fused NeRF: 1 WAVE per ray, 2 rays/block (128 thr), no barriers at all ======
// Same-wave DS ops complete in order; compiler inserts VGPR-hazard lgkmcnt waits.
// All RAW/WAR pairs are within a single __shared__ array, so the compiler cannot
// reorder them either. No explicit s_waitcnt drains needed.
__global__ __launch_bounds__(128) void nerf_fused(
    const float* __restrict__ ro, const float* __restrict__ rd,
    const float* __restrict__ b1, const float* __restrict__ b2,
    const float* __restrict__ bc1, const float* __restrict__ bc2,
    const unsigned short* __restrict__ wb, float* __restrict__ out)
{
  __shared__ __align__(16) unsigned short Hfrag[2][2][1024];  // 8 KB
  __shared__ __align__(16) unsigned short GeoAll[2][4096];    // 16 KB: od0..15 per sample
  __shared__ __align__(16) unsigned short sig16[2][256];      // 1 KB: f16 sigma (coarse+fine)
  __shared__ __align__(16) float zBs[2][128];                 // 1 KB
  __shared__ __align__(16) float zMc[2][264];                 // ~2 KB: cdf (early) / zM+oid (late)
  __shared__ __align__(16) float wL[2][256];                  // 2 KB

  const int tid = threadIdx.x, lane = tid&63, wv = tid>>6;
  const int q = lane>>4, c = lane&15;
  const int r = blockIdx.x*2 + wv;

  float ox,oy,oz,dx,dy,dz;
  load_ray(ro,rd,r,ox,oy,oz,dx,dy,dz);
  float nears,fars; aabb_nf(ox,oy,oz,dx,dy,dz,nears,fars);
  const float step  = (fars-nears)*(1.f/127.f);
  const float sdist = (fars-nears)*(1.f/128.f);
  const bool asc = (nears <= fars);

  const half8* WF = (const half8*)wb;
  half8 aW1T[4], aW2T[2], aWc1T[4], aWc2T[2];
  #pragma unroll
  for(int t=0;t<4;t++){ aW1T[t] = WF[t*64+lane]; aWc1T[t] = WF[(6+t)*64+lane]; }
  #pragma unroll
  for(int k=0;k<2;k++){ aW2T[k] = WF[(4+k)*64+lane]; aWc2T[k] = WF[(10+k)*64+lane]; }
  float4_ b1v[4], bc1v[4];
  #pragma unroll
  for(int t=0;t<4;t++){
    b1v[t]  = *(const float4_*)&b1[t*16+q*4];
    bc1v[t] = *(const float4_*)&bc1[t*16+q*4];
  }
  const float4_ bTd = *(const float4_*)&b2[q*4];
  float4_ bTc = (float4_){0.f,0.f,0.f,0.f};
  if (q==0){ bTc[0]=bc2[0]; bTc[1]=bc2[1]; bTc[2]=bc2[2]; }

  unsigned short* H0 = &Hfrag[wv][0][0];
  unsigned short* H1 = &Hfrag[wv][1][0];
  unsigned short* Geo = &GeoAll[wv][0];
  unsigned short* sgw = sig16[wv];
  float* zBsw = zBs[wv];
  float* cdfw = zMc[wv];          // alias: cdf lives here until merge overwrites
  float* zMw  = zMc[wv];          // merged z (low 8 bits = origin id)
  float* wLw  = wL[wv];
  const int hbase = (q>>1)*128 + c*8 + (q&1)*4;   // ushort index (writer)
  const int lread = lane*8;                        // ushort index (reader)

  // ---------- pass 0: coarse density (4 pair-iterations) ----------
  #pragma unroll
  for(int p=0;p<4;p++){
    const int sidx0 = p*32 + c, sidx1 = p*32 + 16 + c;
    half8 bf0 = (half8)(_Float16)0, bf1 = (half8)(_Float16)0;
    if (q==0){
      float z0 = fmaf(step,(float)sidx0,nears);
      float z1 = fmaf(step,(float)sidx1,nears);
      unsigned int* u0p = (unsigned int*)&bf0;
      u0p[0] = pkh(clip1(fmaf(dx,z0,ox)), clip1(fmaf(dy,z0,oy)));
      u0p[1] = pkh(clip1(fmaf(dz,z0,oz)), 0.f);
      unsigned int* u1p = (unsigned int*)&bf1;
      u1p[0] = pkh(clip1(fmaf(dx,z1,ox)), clip1(fmaf(dy,z1,oy)));
      u1p[1] = pkh(clip1(fmaf(dz,z1,oz)), 0.f);
    }
    #pragma unroll
    for(int t=0;t<4;t++){
      float4_ a0 = __builtin_amdgcn_mfma_f32_16x16x32_f16(aW1T[t], bf0, b1v[t], 0,0,0);
      float4_ a1 = __builtin_amdgcn_mfma_f32_16x16x32_f16(aW1T[t], bf1, b1v[t], 0,0,0);
      storeH(H0, a0, t, hbase);
      storeH(H1, a1, t, hbase);
    }
    half8 h00 = *(const half8*)&H0[lread];
    half8 h01 = *(const half8*)&H0[512 + lread];
    half8 h10 = *(const half8*)&H1[lread];
    half8 h11 = *(const half8*)&H1[512 + lread];
    float4_ o0 = __builtin_amdgcn_mfma_f32_16x16x32_f16(aW2T[0], h00, bTd, 0,0,0);
    o0 = __builtin_amdgcn_mfma_f32_16x16x32_f16(aW2T[1], h01, o0, 0,0,0);
    float4_ o1 = __builtin_amdgcn_mfma_f32_16x16x32_f16(aW2T[0], h10, bTd, 0,0,0);
    o1 = __builtin_amdgcn_mfma_f32_16x16x32_f16(aW2T[1], h11, o1, 0,0,0);
    *(unsigned long long*)&Geo[sidx0*16 + q*4] = pk64(o0);
    *(unsigned long long*)&Geo[sidx1*16 + q*4] = pk64(o1);
    if (q==0){
      sgw[sidx0] = __half_as_ushort(__float2half_rn(softplusf_(o0[0])));
      sgw[sidx1] = __half_as_ushort(__float2half_rn(softplusf_(o1[0])));
    }
  }

  // ---------- pdf: wave-local exp-space scan + cdf (2 elems/lane) ----------
  {
    union { unsigned int u; __half2 h; } sp;
    sp.u = *(const unsigned int*)&sgw[2*lane];
    float s0 = __half2float(__low2half(sp.h));
    float s1 = __half2float(__high2half(sp.h));
    float d0 = (2*lane   < 127) ? step*s0 : 0.f;
    float d1 = (2*lane+1 < 127) ? step*s1 : 0.f;
    float tot;
    float e0 = wave_excl_chunk(d0+d1, lane, tot);
    float w0 = (1.f-__expf(-d0))*__expf(-e0);
    float w1 = (1.f-__expf(-d1))*__expf(-(e0+d0));
    float ww0 = (lane>=1 && 2*lane<127) ? w0+1e-5f : 0.f;   // i=0 excluded
    float ww1 = (2*lane+1 < 127) ? w1+1e-5f : 0.f;
    float wsum;
    float ce0 = wave_excl_chunk(ww0+ww1, lane, wsum);
    float inv = __fdividef(1.f, wsum);
    cdfw[2*lane]   = (ce0+ww0)*inv;
    cdfw[2*lane+1] = (ce0+ww0+ww1)*inv;                     // cdf[127] written, never read
  }

  // ---------- inverse-CDF sampling (2 fine samples/lane), stored z-sorted ----------
  {
    const float u0c = 0.5f/128.f;
    const float du = (1.f - 1.f/128.f)/127.f;
    #pragma unroll
    for(int j=0;j<2;j++){
      int k = lane + j*64;
      float u = fmaf(du,(float)k,u0c);
      int lo=0, hi=127;
      while(lo<hi){ int m=(lo+hi)>>1; if (cdfw[m] <= u) lo=m+1; else hi=m; }
      int below = max(lo-1,0), above = min(lo,126);
      float c0 = cdfw[below], c1 = cdfw[above];
      float bb0 = nears + step*((float)below + 0.5f);
      float bb1 = nears + step*((float)above + 0.5f);
      float den = c1 - c0; if (den < 1e-5f) den = 1.f;
      float zf = bb0 + (u - c0)/den*(bb1 - bb0);
      zBsw[asc ? k : 127-k] = zf;
    }
  }

  // ---------- pass 1: fine density, processed in z-sorted order ----------
  #pragma unroll
  for(int p=0;p<4;p++){
    const int sidx0 = p*32 + c, sidx1 = p*32 + 16 + c;
    half8 bf0 = (half8)(_Float16)0, bf1 = (half8)(_Float16)0;
    if (q==0){
      float z0 = zBsw[sidx0];
      float z1 = zBsw[sidx1];
      unsigned int* u0p = (unsigned int*)&bf0;
      u0p[0] = pkh(clip1(fmaf(dx,z0,ox)), clip1(fmaf(dy,z0,oy)));
      u0p[1] = pkh(clip1(fmaf(dz,z0,oz)), 0.f);
      unsigned int* u1p = (unsigned int*)&bf1;
      u1p[0] = pkh(clip1(fmaf(dx,z1,ox)), clip1(fmaf(dy,z1,oy)));
      u1p[1] = pkh(clip1(fmaf(dz,z1,oz)), 0.f);
    }
    #pragma unroll
    for(int t=0;t<4;t++){
      float4_ a0 = __builtin_amdgcn_mfma_f32_16x16x32_f16(aW1T[t], bf0, b1v[t], 0,0,0);
      float4_ a1 = __builtin_amdgcn_mfma_f32_16x16x32_f16(aW1T[t], bf1, b1v[t], 0,0,0);
      storeH(H0, a0, t, hbase);
      storeH(H1, a1, t, hbase);
    }
    half8 h00 = *(const half8*)&H0[lread];
    half8 h01 = *(const half8*)&H0[512 + lread];
    half8 h10 = *(const half8*)&H1[lread];
    half8 h11 = *(const half8*)&H1[512 + lread];
    float4_ o0 = __builtin_amdgcn_mfma_f32_16x16x32_f16(aW2T[0], h00, bTd, 0,0,0);
    o0 = __builtin_amdgcn_mfma_f32_16x16x32_f16(aW2T[1], h01, o0, 0,0,0);
    float4_ o1 = __builtin_amdgcn_mfma_f32_16x16x32_f16(aW2T[0], h10, bTd, 0,0,0);
    o1 = __builtin_amdgcn_mfma_f32_16x16x32_f16(aW2T[1], h11, o1, 0,0,0);
    *(unsigned long long*)&Geo[(128+sidx0)*16 + q*4] = pk64(o0);
    *(unsigned long long*)&Geo[(128+sidx1)*16 + q*4] = pk64(o1);
    if (q==0){
      sgw[128+sidx0] = __half_as_ushort(__float2half_rn(softplusf_(o0[0])));
      sgw[128+sidx1] = __half_as_ushort(__float2half_rn(softplusf_(o1[0])));
    }
  }

  // ---------- merge: rank by binary search; write z with oid packed in low 8 bits ----------
  #pragma unroll
  for(int j=0;j<2;j++){
    int sA = lane + j*64;
    int i = asc ? sA : 127-sA;
    float myz = fmaf(step,(float)i,nears);
    int lo=0, hi=128;
    while(lo<hi){ int m=(lo+hi)>>1; if (zBsw[m] < myz) lo=m+1; else hi=m; }
    int pos = sA + lo;
    zMw[pos] = __uint_as_float((__float_as_uint(myz) & ~255u) | (unsigned)i);
  }
  #pragma unroll
  for(int j=0;j<2;j++){
    int k = lane + j*64;
    float myz = zBsw[k];
    int lo=0, hi=128;                 // register-only search over computed coarse z
    while(lo<hi){
      int m=(lo+hi)>>1;
      float Am = fmaf(step,(float)(asc?m:127-m),nears);
      if (Am <= myz) lo=m+1; else hi=m;
    }
    int pos = k + lo;
    zMw[pos] = __uint_as_float((__float_as_uint(myz) & ~255u) | (unsigned)(128+k));
  }

  // ---------- composite: wave-local exp-space scan (4 elems/lane), sigma via oid ----------
  {
    float4_ z4 = *(const float4_*)&zMw[4*lane];
    float z5 = zMw[4*lane+4];                      // lane63 reads pad (unused via select)
    float sg0 = __half2float(*(const __half*)&sgw[__float_as_uint(z4[0]) & 255u]);
    float sg1 = __half2float(*(const __half*)&sgw[__float_as_uint(z4[1]) & 255u]);
    float sg2 = __half2float(*(const __half*)&sgw[__float_as_uint(z4[2]) & 255u]);
    float sg3 = __half2float(*(const __half*)&sgw[__float_as_uint(z4[3]) & 255u]);
    float d0 = (z4[1]-z4[0])*sg0;
    float d1 = (z4[2]-z4[1])*sg1;
    float d2 = (z4[3]-z4[2])*sg2;
    float dl = (lane==63) ? sdist : (z5 - z4[3]);
    float d3 = dl*sg3;
    float tot;
    float S = wave_excl_chunk(d0+d1+d2+d3, lane, tot);
    float4_ w4;
    w4[0] = (1.f-__expf(-d0))*__expf(-S); S += d0;
    w4[1] = (1.f-__expf(-d1))*__expf(-S); S += d1;
    w4[2] = (1.f-__expf(-d2))*__expf(-S); S += d2;
    w4[3] = (1.f-__expf(-d3))*__expf(-S);
    *(float4_*)&wLw[4*lane] = w4;
  }

  // ---------- render: color MLP only (geo gathered via packed oid), 8 pair-iterations ----------
  float accR=0.f, accG=0.f, accB=0.f, accW=0.f;
  #pragma unroll
  for(int p=0;p<8;p++){
    const int sidx0 = p*32 + c, sidx1 = p*32 + 16 + c;
    float z0 = zMw[sidx0], z1 = zMw[sidx1];
    int o0i = (int)(__float_as_uint(z0) & 255u);
    int o1i = (int)(__float_as_uint(z1) & 255u);
    float x0 = clip1(fmaf(dx,z0,ox)), y0 = clip1(fmaf(dy,z0,oy)), w0 = clip1(fmaf(dz,z0,oz));
    float x1 = clip1(fmaf(dx,z1,ox)), y1 = clip1(fmaf(dy,z1,oy)), w1 = clip1(fmaf(dz,z1,oz));
    half8 bcf0 = (half8)(_Float16)0, bcf1 = (half8)(_Float16)0;
    if (q < 2){
      bcf0 = *(const half8*)&Geo[o0i*16 + q*8];    // k0..15: [od0(dead), geo0..14]
      bcf1 = *(const half8*)&Geo[o1i*16 + q*8];
    } else if (q == 2){
      unsigned int* u0p = (unsigned int*)&bcf0;    // k16..21 = pos/dir
      u0p[0] = pkh(x0,y0); u0p[1] = pkh(w0,dx); u0p[2] = pkh(dy,dz); u0p[3] = 0u;
      unsigned int* u1p = (unsigned int*)&bcf1;
      u1p[0] = pkh(x1,y1); u1p[1] = pkh(w1,dx); u1p[2] = pkh(dy,dz); u1p[3] = 0u;
    }
    #pragma unroll
    for(int t=0;t<4;t++){
      float4_ a0 = __builtin_amdgcn_mfma_f32_16x16x32_f16(aWc1T[t], bcf0, bc1v[t], 0,0,0);
      float4_ a1 = __builtin_amdgcn_mfma_f32_16x16x32_f16(aWc1T[t], bcf1, bc1v[t], 0,0,0);
      storeH(H0, a0, t, hbase);
      storeH(H1, a1, t, hbase);
    }
    half8 h00 = *(const half8*)&H0[lread];
    half8 h01 = *(const half8*)&H0[512 + lread];
    half8 h10 = *(const half8*)&H1[lread];
    half8 h11 = *(const half8*)&H1[512 + lread];
    float4_ oc0 = __builtin_amdgcn_mfma_f32_16x16x32_f16(aWc2T[0], h00, bTc, 0,0,0);
    oc0 = __builtin_amdgcn_mfma_f32_16x16x32_f16(aWc2T[1], h01, oc0, 0,0,0);
    float4_ oc1 = __builtin_amdgcn_mfma_f32_16x16x32_f16(aWc2T[0], h10, bTc, 0,0,0);
    oc1 = __builtin_amdgcn_mfma_f32_16x16x32_f16(aWc2T[1], h11, oc1, 0,0,0);
    if (q==0){
      float g0w = wLw[sidx0];
      if (g0w > 1e-4f){
        accR = fmaf(g0w, sigmoidf_(oc0[0]), accR);
        accG = fmaf(g0w, sigmoidf_(oc0[1]), accG);
        accB = fmaf(g0w, sigmoidf_(oc0[2]), accB);
      }
      accW += g0w;
      float g1w = wLw[sidx1];
      if (g1w > 1e-4f){
        accR = fmaf(g1w, sigmoidf_(oc1[0]), accR);
        accG = fmaf(g1w, sigmoidf_(oc1[1]), accG);
        accB = fmaf(g1w, sigmoidf_(oc1[2]), accB);
      }
      accW += g1w;
    }
  }

  // ---------- wave reduce + output ----------
  #pragma unroll
  for(int off=32; off; off>>=1){
    accR += __shfl_down(accR, off, 64);
    accG += __shfl_down(accG, off, 64);
    accB += __shfl_down(accB, off, 64);
    accW += __shfl_down(accW, off, 64);
  }
  if (lane == 0){
    float bg = 1.f - accW;
    out[r*3+0] = accR + bg;
    out[r*3+1] = accG + bg;
    out[r*3+2] = accB + bg;
  }
}

extern "C" void kernel_launch(void* const* d_in, const int* in_sizes, int n_in,
                              void* d_out, int out_size, void* d_ws, size_t ws_size,
                              hipStream_t stream) {
  const float* ro  = (const float*)d_in[0];
  const float* rd  = (const float*)d_in[1];
  const float* W1  = (const float*)d_in[2];
  const float* b1  = (const float*)d_in[3];
  const float* W2  = (const float*)d_in[4];
  const float* b2  = (const float*)d_in[5];
  const float* Wc1 = (const float*)d_in[6];
  const float* bc1 = (const float*)d_in[7];
  const float* Wc2 = (const float*)d_in[8];
  const float* bc2 = (const float*)d_in[9];
  float* out = (float*)d_out;

  unsigned short* wb = (unsigned short*)d_ws;   // 6144 f16 fragment words

  prep_weights<<<dim3(24), dim3(256), 0, stream>>>(W1, W2, Wc1, Wc2, wb);
  nerf_fused<<<dim3(NRAYS/2), dim3(128), 0, stream>>>(
      ro, rd, b1, b2, bc1, bc2, wb, out);
}

// Round 15
// 202.416 us; speedup vs baseline: 1.7783x; 1.0073x over previous
//
#include <hip/hip_runtime.h>
#include <hip/hip_fp16.h>
#include <math.h>

#define NRAYS 16384
#define HID 64

typedef float    float4_ __attribute__((ext_vector_type(4)));
typedef _Float16 half8   __attribute__((ext_vector_type(8)));
typedef __fp16   fp16x2  __attribute__((ext_vector_type(2)));

__device__ __forceinline__ float clip1(float v){ return fminf(fmaxf(v,-1.f),1.f); }
__device__ __forceinline__ float softplusf_(float x){
  return fmaxf(x,0.f) + __logf(1.f + __expf(-fabsf(x)));
}
__device__ __forceinline__ float sigmoidf_(float x){
  return __fdividef(1.f, 1.f + __expf(-x));
}

// 1-inst HW pack: 2 floats -> 2 f16 (RTZ). a -> low16, b -> high16.
__device__ __forceinline__ unsigned int pkh(float a, float b){
  union { fp16x2 h; unsigned int u; } cv;
  cv.h = __builtin_amdgcn_cvt_pkrtz(a, b);
  return cv.u;
}
__device__ __forceinline__ unsigned long long pk64(float4_ a){
  return (unsigned long long)pkh(a[0],a[1]) | ((unsigned long long)pkh(a[2],a[3])<<32);
}
// packed relu on 2 f16 lanes in one VOP3P inst
__device__ __forceinline__ unsigned int relu_pk(unsigned int x){
  unsigned int y;
  __asm__("v_pk_max_f16 %0, %1, 0" : "=v"(y) : "v"(x));
  return y;
}

__device__ __forceinline__ void load_ray(const float* ro, const float* rd, int r,
    float& ox,float& oy,float& oz,float& dx,float& dy,float& dz){
  ox=ro[3*r]; oy=ro[3*r+1]; oz=ro[3*r+2];
  dx=rd[3*r]; dy=rd[3*r+1]; dz=rd[3*r+2];
  float inv = 1.f/sqrtf(dx*dx+dy*dy+dz*dz);
  dx*=inv; dy*=inv; dz*=inv;
}

__device__ __forceinline__ void aabb_nf(float ox,float oy,float oz,float dx,float dy,float dz,
    float& nears,float& fars){
  float dsx = (fabsf(dx)<1e-8f)?1e-8f:dx;
  float dsy = (fabsf(dy)<1e-8f)?1e-8f:dy;
  float dsz = (fabsf(dz)<1e-8f)?1e-8f:dz;
  float t1x=(-1.f-ox)/dsx, t2x=(1.f-ox)/dsx;
  float t1y=(-1.f-oy)/dsy, t2y=(1.f-oy)/dsy;
  float t1z=(-1.f-oz)/dsz, t2z=(1.f-oz)/dsz;
  float nr = fmaxf(fmaxf(fminf(t1x,t2x),fminf(t1y,t2y)),fminf(t1z,t2z));
  float fr = fminf(fminf(fmaxf(t1x,t2x),fmaxf(t1y,t2y)),fmaxf(t1z,t2z));
  fars  = fmaxf(fminf(fr,5.f),0.2f);
  nears = fminf(fmaxf(nr,0.2f),5.f);
}

// wave-level exclusive scan over per-lane chunk sums; no barriers.
__device__ __forceinline__ float wave_excl_chunk(float chunk, int lane, float& total){
  float incl = chunk;
  #pragma unroll
  for(int off=1; off<64; off<<=1){
    float n = __shfl_up(incl, off, 64);
    if (lane >= off) incl += n;
  }
  total = __shfl(incl, 63, 64);
  return incl - chunk;
}

// ---------------- weight prep: f16 A-fragments (transposed weights) ----------------
// A-frag: lane l holds A[m=l&15][k=(l>>4)*8+j]. 12 slots of 64 lanes x 8 halves:
// slots 0..3 : W1^T  (M-tile mt: m=h=mt*16+c):  A = W1[k][h], k>=3 -> 0
// slots 4..5 : W2^T  (K-step ks: k=h=ks*32+..): A = W2[h][od=c]
// slots 6..9 : Wc1^T (M-tile mt), PERMUTED k:   k=0 -> 0 row (od0=sigma unused);
//              k in 1..15 -> geo_{k-1} (Wc1 row 5+k); k in 16..21 -> pos/dir
//              (Wc1 row k-16); k>=22 -> 0
// slots 10..11: Wc2^T: A = (c<3)? Wc2[h][c] : 0
__global__ void prep_weights(const float* __restrict__ W1, const float* __restrict__ W2,
                             const float* __restrict__ Wc1, const float* __restrict__ Wc2,
                             unsigned short* __restrict__ wb){
  int idx = blockIdx.x*256 + threadIdx.x;
  if (idx >= 6144) return;
  int f = idx>>3, j = idx&7, lane = f&63, slot = f>>6, q = lane>>4, c = lane&15;
  int k = q*8+j;
  float v = 0.f;
  if (slot < 4){        if (k<3) v = W1[k*HID + slot*16 + c]; }
  else if (slot < 6){   int h=(slot-4)*32+k; v = W2[h*16 + c]; }
  else if (slot < 10){  int mt=slot-6;
                        int row = (k==0)? -1 : (k<16 ? 5+k : (k<22 ? k-16 : -1));
                        if (row>=0) v = Wc1[row*HID + mt*16 + c]; }
  else {                int h=(slot-10)*32+k; if (c<3) v = Wc2[h*3 + c]; }
  wb[idx] = __half_as_ushort(__float2half_rn(v));
}

// pack a layer-1 C-tile (4 h-rows, sample c) + packed relu -> one b64 into frag-major H
__device__ __forceinline__ void storeH(unsigned short* H, float4_ a, int t, int hbase){
  unsigned int lo = relu_pk(pkh(a[0],a[1]));
  unsigned int hi = relu_pk(pkh(a[2],a[3]));
  *(unsigned long long*)&H[hbase + t*256] =
      (unsigned long long)lo | ((unsigned long long)hi<<32);
}

// ====== fully fused NeRF: 1 WAVE per ray, 2 rays/block (128 thr), no barriers at all ======
__global__ __launch_bounds__(128) void nerf_fused(
    const float* __restrict__ ro, const float* __restrict__ rd,
    const float* __restrict__ b1, const float* __restrict__ b2,
    const float* __restrict__ bc1, const float* __restrict__ bc2,
    const unsigned short* __restrict__ wb, float* __restrict__ out)
{
  __shared__ __align__(16) unsigned short Hfrag[2][2][1024];  // 8 KB
  __shared__ __align__(16) unsigned short GeoAll[2][4096];    // 16 KB: od0..15 per sample
  __shared__ __align__(16) unsigned short sig16[2][256];      // 1 KB: f16 sigma (coarse+fine)
  __shared__ __align__(16) float zBs[2][128];                 // 1 KB
  __shared__ __align__(16) float zMc[2][264];                 // ~2 KB: cdf (early) / zM+oid (late)
  __shared__ __align__(16) float wL[2][256];                  // 2 KB

  const int tid = threadIdx.x, lane = tid&63, wv = tid>>6;
  const int q = lane>>4, c = lane&15;
  const int r = blockIdx.x*2 + wv;

  float ox,oy,oz,dx,dy,dz;
  load_ray(ro,rd,r,ox,oy,oz,dx,dy,dz);
  float nears,fars; aabb_nf(ox,oy,oz,dx,dy,dz,nears,fars);
  const float step  = (fars-nears)*(1.f/127.f);
  const float sdist = (fars-nears)*(1.f/128.f);
  const bool asc = (nears <= fars);

  const half8* WF = (const half8*)wb;
  half8 aW1T[4], aW2T[2], aWc1T[4], aWc2T[2];
  #pragma unroll
  for(int t=0;t<4;t++){ aW1T[t] = WF[t*64+lane]; aWc1T[t] = WF[(6+t)*64+lane]; }
  #pragma unroll
  for(int k=0;k<2;k++){ aW2T[k] = WF[(4+k)*64+lane]; aWc2T[k] = WF[(10+k)*64+lane]; }
  float4_ b1v[4], bc1v[4];
  #pragma unroll
  for(int t=0;t<4;t++){
    b1v[t]  = *(const float4_*)&b1[t*16+q*4];
    bc1v[t] = *(const float4_*)&bc1[t*16+q*4];
  }
  const float4_ bTd = *(const float4_*)&b2[q*4];
  float4_ bTc = (float4_){0.f,0.f,0.f,0.f};
  if (q==0){ bTc[0]=bc2[0]; bTc[1]=bc2[1]; bTc[2]=bc2[2]; }

  unsigned short* H0 = &Hfrag[wv][0][0];
  unsigned short* H1 = &Hfrag[wv][1][0];
  unsigned short* Geo = &GeoAll[wv][0];
  unsigned short* sgw = sig16[wv];
  float* zBsw = zBs[wv];
  float* cdfw = zMc[wv];          // alias: cdf lives here until merge overwrites
  float* zMw  = zMc[wv];          // merged z (low 8 bits = origin id)
  float* wLw  = wL[wv];
  const int hbase = (q>>1)*128 + c*8 + (q&1)*4;   // ushort index (writer)
  const int lread = lane*8;                        // ushort index (reader)

  // ---------- pass 0: coarse density (4 pair-iterations) ----------
  #pragma unroll
  for(int p=0;p<4;p++){
    const int sidx0 = p*32 + c, sidx1 = p*32 + 16 + c;
    half8 bf0 = (half8)(_Float16)0, bf1 = (half8)(_Float16)0;
    if (q==0){
      float z0 = fmaf(step,(float)sidx0,nears);
      float z1 = fmaf(step,(float)sidx1,nears);
      unsigned int* u0p = (unsigned int*)&bf0;
      u0p[0] = pkh(clip1(fmaf(dx,z0,ox)), clip1(fmaf(dy,z0,oy)));
      u0p[1] = pkh(clip1(fmaf(dz,z0,oz)), 0.f);
      unsigned int* u1p = (unsigned int*)&bf1;
      u1p[0] = pkh(clip1(fmaf(dx,z1,ox)), clip1(fmaf(dy,z1,oy)));
      u1p[1] = pkh(clip1(fmaf(dz,z1,oz)), 0.f);
    }
    #pragma unroll
    for(int t=0;t<4;t++){
      float4_ a0 = __builtin_amdgcn_mfma_f32_16x16x32_f16(aW1T[t], bf0, b1v[t], 0,0,0);
      float4_ a1 = __builtin_amdgcn_mfma_f32_16x16x32_f16(aW1T[t], bf1, b1v[t], 0,0,0);
      storeH(H0, a0, t, hbase);
      storeH(H1, a1, t, hbase);
    }
    half8 h00 = *(const half8*)&H0[lread];
    half8 h01 = *(const half8*)&H0[512 + lread];
    half8 h10 = *(const half8*)&H1[lread];
    half8 h11 = *(const half8*)&H1[512 + lread];
    float4_ o0 = __builtin_amdgcn_mfma_f32_16x16x32_f16(aW2T[0], h00, bTd, 0,0,0);
    o0 = __builtin_amdgcn_mfma_f32_16x16x32_f16(aW2T[1], h01, o0, 0,0,0);
    float4_ o1 = __builtin_amdgcn_mfma_f32_16x16x32_f16(aW2T[0], h10, bTd, 0,0,0);
    o1 = __builtin_amdgcn_mfma_f32_16x16x32_f16(aW2T[1], h11, o1, 0,0,0);
    *(unsigned long long*)&Geo[sidx0*16 + q*4] = pk64(o0);
    *(unsigned long long*)&Geo[sidx1*16 + q*4] = pk64(o1);
    if (q==0){
      sgw[sidx0] = __half_as_ushort(__float2half_rn(softplusf_(o0[0])));
      sgw[sidx1] = __half_as_ushort(__float2half_rn(softplusf_(o1[0])));
    }
  }

  // ---------- pdf: wave-local exp-space scan + cdf (2 elems/lane) ----------
  {
    union { unsigned int u; __half2 h; } sp;
    sp.u = *(const unsigned int*)&sgw[2*lane];
    float s0 = __half2float(__low2half(sp.h));
    float s1 = __half2float(__high2half(sp.h));
    float d0 = (2*lane   < 127) ? step*s0 : 0.f;
    float d1 = (2*lane+1 < 127) ? step*s1 : 0.f;
    float tot;
    float e0 = wave_excl_chunk(d0+d1, lane, tot);
    float w0 = (1.f-__expf(-d0))*__expf(-e0);
    float w1 = (1.f-__expf(-d1))*__expf(-(e0+d0));
    float ww0 = (lane>=1 && 2*lane<127) ? w0+1e-5f : 0.f;   // i=0 excluded
    float ww1 = (2*lane+1 < 127) ? w1+1e-5f : 0.f;
    float wsum;
    float ce0 = wave_excl_chunk(ww0+ww1, lane, wsum);
    float inv = __fdividef(1.f, wsum);
    cdfw[2*lane]   = (ce0+ww0)*inv;
    cdfw[2*lane+1] = (ce0+ww0+ww1)*inv;                     // cdf[127] written, never read
  }

  // ---------- inverse-CDF sampling (2 fine samples/lane), stored z-sorted ----------
  {
    const float u0c = 0.5f/128.f;
    const float du = (1.f - 1.f/128.f)/127.f;
    #pragma unroll
    for(int j=0;j<2;j++){
      int k = lane + j*64;
      float u = fmaf(du,(float)k,u0c);
      int lo=0, hi=127;
      while(lo<hi){ int m=(lo+hi)>>1; if (cdfw[m] <= u) lo=m+1; else hi=m; }
      int below = max(lo-1,0), above = min(lo,126);
      float c0 = cdfw[below], c1 = cdfw[above];
      float bb0 = nears + step*((float)below + 0.5f);
      float bb1 = nears + step*((float)above + 0.5f);
      float den = c1 - c0; if (den < 1e-5f) den = 1.f;
      float zf = bb0 + (u - c0)/den*(bb1 - bb0);
      zBsw[asc ? k : 127-k] = zf;
    }
  }

  // ---------- pass 1: fine density, processed in z-sorted order ----------
  #pragma unroll
  for(int p=0;p<4;p++){
    const int sidx0 = p*32 + c, sidx1 = p*32 + 16 + c;
    half8 bf0 = (half8)(_Float16)0, bf1 = (half8)(_Float16)0;
    if (q==0){
      float z0 = zBsw[sidx0];
      float z1 = zBsw[sidx1];
      unsigned int* u0p = (unsigned int*)&bf0;
      u0p[0] = pkh(clip1(fmaf(dx,z0,ox)), clip1(fmaf(dy,z0,oy)));
      u0p[1] = pkh(clip1(fmaf(dz,z0,oz)), 0.f);
      unsigned int* u1p = (unsigned int*)&bf1;
      u1p[0] = pkh(clip1(fmaf(dx,z1,ox)), clip1(fmaf(dy,z1,oy)));
      u1p[1] = pkh(clip1(fmaf(dz,z1,oz)), 0.f);
    }
    #pragma unroll
    for(int t=0;t<4;t++){
      float4_ a0 = __builtin_amdgcn_mfma_f32_16x16x32_f16(aW1T[t], bf0, b1v[t], 0,0,0);
      float4_ a1 = __builtin_amdgcn_mfma_f32_16x16x32_f16(aW1T[t], bf1, b1v[t], 0,0,0);
      storeH(H0, a0, t, hbase);
      storeH(H1, a1, t, hbase);
    }
    half8 h00 = *(const half8*)&H0[lread];
    half8 h01 = *(const half8*)&H0[512 + lread];
    half8 h10 = *(const half8*)&H1[lread];
    half8 h11 = *(const half8*)&H1[512 + lread];
    float4_ o0 = __builtin_amdgcn_mfma_f32_16x16x32_f16(aW2T[0], h00, bTd, 0,0,0);
    o0 = __builtin_amdgcn_mfma_f32_16x16x32_f16(aW2T[1], h01, o0, 0,0,0);
    float4_ o1 = __builtin_amdgcn_mfma_f32_16x16x32_f16(aW2T[0], h10, bTd, 0,0,0);
    o1 = __builtin_amdgcn_mfma_f32_16x16x32_f16(aW2T[1], h11, o1, 0,0,0);
    *(unsigned long long*)&Geo[(128+sidx0)*16 + q*4] = pk64(o0);
    *(unsigned long long*)&Geo[(128+sidx1)*16 + q*4] = pk64(o1);
    if (q==0){
      sgw[128+sidx0] = __half_as_ushort(__float2half_rn(softplusf_(o0[0])));
      sgw[128+sidx1] = __half_as_ushort(__float2half_rn(softplusf_(o1[0])));
    }
  }

  // ---------- merge: rank by binary search; write z with oid packed in low 8 bits ----------
  #pragma unroll
  for(int j=0;j<2;j++){
    int sA = lane + j*64;
    int i = asc ? sA : 127-sA;
    float myz = fmaf(step,(float)i,nears);
    int lo=0, hi=128;
    while(lo<hi){ int m=(lo+hi)>>1; if (zBsw[m] < myz) lo=m+1; else hi=m; }
    int pos = sA + lo;
    zMw[pos] = __uint_as_float((__float_as_uint(myz) & ~255u) | (unsigned)i);
  }
  #pragma unroll
  for(int j=0;j<2;j++){
    int k = lane + j*64;
    float myz = zBsw[k];
    int lo=0, hi=128;                 // register-only search over computed coarse z
    while(lo<hi){
      int m=(lo+hi)>>1;
      float Am = fmaf(step,(float)(asc?m:127-m),nears);
      if (Am <= myz) lo=m+1; else hi=m;
    }
    int pos = k + lo;
    zMw[pos] = __uint_as_float((__float_as_uint(myz) & ~255u) | (unsigned)(128+k));
  }

  // ---------- composite: wave-local exp-space scan (4 elems/lane), sigma via oid ----------
  {
    float4_ z4 = *(const float4_*)&zMw[4*lane];
    float z5 = zMw[4*lane+4];                      // lane63 reads pad (unused via select)
    float sg0 = __half2float(*(const __half*)&sgw[__float_as_uint(z4[0]) & 255u]);
    float sg1 = __half2float(*(const __half*)&sgw[__float_as_uint(z4[1]) & 255u]);
    float sg2 = __half2float(*(const __half*)&sgw[__float_as_uint(z4[2]) & 255u]);
    float sg3 = __half2float(*(const __half*)&sgw[__float_as_uint(z4[3]) & 255u]);
    float d0 = (z4[1]-z4[0])*sg0;
    float d1 = (z4[2]-z4[1])*sg1;
    float d2 = (z4[3]-z4[2])*sg2;
    float dl = (lane==63) ? sdist : (z5 - z4[3]);
    float d3 = dl*sg3;
    float tot;
    float S = wave_excl_chunk(d0+d1+d2+d3, lane, tot);
    float4_ w4;
    w4[0] = (1.f-__expf(-d0))*__expf(-S); S += d0;
    w4[1] = (1.f-__expf(-d1))*__expf(-S); S += d1;
    w4[2] = (1.f-__expf(-d2))*__expf(-S); S += d2;
    w4[3] = (1.f-__expf(-d3))*__expf(-S);
    *(float4_*)&wLw[4*lane] = w4;
  }

  // ---------- render: color MLP only (geo gathered via packed oid), 8 pair-iterations
  //            with wave-uniform skip of fully-masked groups (w<=1e-4 everywhere) ----------
  float accR=0.f, accG=0.f, accB=0.f, accW=0.f;
  #pragma unroll
  for(int p=0;p<8;p++){
    const int sidx0 = p*32 + c, sidx1 = p*32 + 16 + c;
    float g0w = wLw[sidx0];
    float g1w = wLw[sidx1];
    if (q==0){ accW += g0w + g1w; }
    // skip whole group's color MLP if no sample is visible (reference zeroes them anyway)
    unsigned long long vis = __ballot((g0w > 1e-4f) || (g1w > 1e-4f));
    if (vis == 0ull) continue;

    float z0 = zMw[sidx0], z1 = zMw[sidx1];
    int o0i = (int)(__float_as_uint(z0) & 255u);
    int o1i = (int)(__float_as_uint(z1) & 255u);
    float x0 = clip1(fmaf(dx,z0,ox)), y0 = clip1(fmaf(dy,z0,oy)), w0 = clip1(fmaf(dz,z0,oz));
    float x1 = clip1(fmaf(dx,z1,ox)), y1 = clip1(fmaf(dy,z1,oy)), w1 = clip1(fmaf(dz,z1,oz));
    half8 bcf0 = (half8)(_Float16)0, bcf1 = (half8)(_Float16)0;
    if (q < 2){
      bcf0 = *(const half8*)&Geo[o0i*16 + q*8];    // k0..15: [od0(dead), geo0..14]
      bcf1 = *(const half8*)&Geo[o1i*16 + q*8];
    } else if (q == 2){
      unsigned int* u0p = (unsigned int*)&bcf0;    // k16..21 = pos/dir
      u0p[0] = pkh(x0,y0); u0p[1] = pkh(w0,dx); u0p[2] = pkh(dy,dz); u0p[3] = 0u;
      unsigned int* u1p = (unsigned int*)&bcf1;
      u1p[0] = pkh(x1,y1); u1p[1] = pkh(w1,dx); u1p[2] = pkh(dy,dz); u1p[3] = 0u;
    }
    #pragma unroll
    for(int t=0;t<4;t++){
      float4_ a0 = __builtin_amdgcn_mfma_f32_16x16x32_f16(aWc1T[t], bcf0, bc1v[t], 0,0,0);
      float4_ a1 = __builtin_amdgcn_mfma_f32_16x16x32_f16(aWc1T[t], bcf1, bc1v[t], 0,0,0);
      storeH(H0, a0, t, hbase);
      storeH(H1, a1, t, hbase);
    }
    half8 h00 = *(const half8*)&H0[lread];
    half8 h01 = *(const half8*)&H0[512 + lread];
    half8 h10 = *(const half8*)&H1[lread];
    half8 h11 = *(const half8*)&H1[512 + lread];
    float4_ oc0 = __builtin_amdgcn_mfma_f32_16x16x32_f16(aWc2T[0], h00, bTc, 0,0,0);
    oc0 = __builtin_amdgcn_mfma_f32_16x16x32_f16(aWc2T[1], h01, oc0, 0,0,0);
    float4_ oc1 = __builtin_amdgcn_mfma_f32_16x16x32_f16(aWc2T[0], h10, bTc, 0,0,0);
    oc1 = __builtin_amdgcn_mfma_f32_16x16x32_f16(aWc2T[1], h11, oc1, 0,0,0);
    if (q==0){
      if (g0w > 1e-4f){
        accR = fmaf(g0w, sigmoidf_(oc0[0]), accR);
        accG = fmaf(g0w, sigmoidf_(oc0[1]), accG);
        accB = fmaf(g0w, sigmoidf_(oc0[2]), accB);
      }
      if (g1w > 1e-4f){
        accR = fmaf(g1w, sigmoidf_(oc1[0]), accR);
        accG = fmaf(g1w, sigmoidf_(oc1[1]), accG);
        accB = fmaf(g1w, sigmoidf_(oc1[2]), accB);
      }
    }
  }

  // ---------- wave reduce + output ----------
  #pragma unroll
  for(int off=32; off; off>>=1){
    accR += __shfl_down(accR, off, 64);
    accG += __shfl_down(accG, off, 64);
    accB += __shfl_down(accB, off, 64);
    accW += __shfl_down(accW, off, 64);
  }
  if (lane == 0){
    float bg = 1.f - accW;
    out[r*3+0] = accR + bg;
    out[r*3+1] = accG + bg;
    out[r*3+2] = accB + bg;
  }
}

extern "C" void kernel_launch(void* const* d_in, const int* in_sizes, int n_in,
                              void* d_out, int out_size, void* d_ws, size_t ws_size,
                              hipStream_t stream) {
  const float* ro  = (const float*)d_in[0];
  const float* rd  = (const float*)d_in[1];
  const float* W1  = (const float*)d_in[2];
  const float* b1  = (const float*)d_in[3];
  const float* W2  = (const float*)d_in[4];
  const float* b2  = (const float*)d_in[5];
  const float* Wc1 = (const float*)d_in[6];
  const float* bc1 = (const float*)d_in[7];
  const float* Wc2 = (const float*)d_in[8];
  const float* bc2 = (const float*)d_in[9];
  float* out = (float*)d_out;

  unsigned short* wb = (unsigned short*)d_ws;   // 6144 f16 fragment words

  prep_weights<<<dim3(24), dim3(256), 0, stream>>>(W1, W2, Wc1, Wc2, wb);
  nerf_fused<<<dim3(NRAYS/2), dim3(128), 0, stream>>>(
      ro, rd, b1, b2, bc1, bc2, wb, out);
}